// Round 1
// baseline (7341.084 us; speedup 1.0000x reference)
//
#include <hip/hip_runtime.h>
#include <math.h>

#define N_NODES  50000
#define N_HEDGES 50000
#define NNZ_     800000
#define IN_CH    512
#define HID_CH   256
#define OUT_CH   64

// ---------------- degree + inverse ----------------
__global__ void degree_kernel(const int* __restrict__ node_idx,
                              const int* __restrict__ hedge_idx,
                              float* __restrict__ D, float* __restrict__ B) {
    int i = blockIdx.x * blockDim.x + threadIdx.x;
    if (i < NNZ_) {
        atomicAdd(&D[node_idx[i]], 1.0f);
        atomicAdd(&B[hedge_idx[i]], 1.0f);
    }
}

__global__ void invert_kernel(float* __restrict__ D, float* __restrict__ B) {
    int i = blockIdx.x * blockDim.x + threadIdx.x;
    if (i < N_NODES)  D[i] = D[i] > 0.f ? 1.f / D[i] : 0.f;
    if (i < N_HEDGES) B[i] = B[i] > 0.f ? 1.f / B[i] : 0.f;
}

// ---------------- fp32 tiled GEMM: C[M,N] = A[M,K] @ B[K,N] ----------------
// 64x64 tile, 16x16 threads, 4x4 microtile, TK=16.
__global__ void gemm_kernel(const float* __restrict__ A, const float* __restrict__ B,
                            float* __restrict__ C, int M, int N, int K) {
    __shared__ float As[16][64 + 1];
    __shared__ float Bs[16][64 + 1];
    const int tx = threadIdx.x;              // 0..15
    const int ty = threadIdx.y;              // 0..15
    const int tid = ty * 16 + tx;
    const int row0 = blockIdx.y * 64;
    const int col0 = blockIdx.x * 64;

    float acc[4][4] = {};

    for (int k0 = 0; k0 < K; k0 += 16) {
        // A tile: 64 rows x 16 k  (1024 elems / 256 threads = 4 each)
        #pragma unroll
        for (int i = tid; i < 64 * 16; i += 256) {
            int r = i >> 4, c = i & 15;
            int gr = row0 + r;
            As[c][r] = (gr < M) ? A[(long long)gr * K + k0 + c] : 0.f;
        }
        // B tile: 16 k x 64 cols
        #pragma unroll
        for (int i = tid; i < 16 * 64; i += 256) {
            int r = i >> 6, c = i & 63;
            Bs[r][c] = B[(long long)(k0 + r) * N + col0 + c];
        }
        __syncthreads();
        #pragma unroll
        for (int k = 0; k < 16; ++k) {
            float a[4], b[4];
            #pragma unroll
            for (int i = 0; i < 4; ++i) a[i] = As[k][ty * 4 + i];
            #pragma unroll
            for (int j = 0; j < 4; ++j) b[j] = Bs[k][tx * 4 + j];
            #pragma unroll
            for (int i = 0; i < 4; ++i)
                #pragma unroll
                for (int j = 0; j < 4; ++j)
                    acc[i][j] += a[i] * b[j];
        }
        __syncthreads();
    }
    #pragma unroll
    for (int i = 0; i < 4; ++i) {
        int gr = row0 + ty * 4 + i;
        if (gr < M) {
            #pragma unroll
            for (int j = 0; j < 4; ++j)
                C[(long long)gr * N + col0 + tx * 4 + j] = acc[i][j];
        }
    }
}

// ---------------- scatter-add (segment_sum via atomics) ----------------
// dst[didx[e]] += src[sidx[e]] * (scale ? scale[sidx[e]] : 1)
template <int C>
__global__ void scatter_kernel(const float* __restrict__ src, float* __restrict__ dst,
                               const int* __restrict__ sidx, const int* __restrict__ didx,
                               const float* __restrict__ scale) {
    constexpr int CP4 = C / 4;
    int gid = blockIdx.x * blockDim.x + threadIdx.x;
    if (gid >= NNZ_ * CP4) return;
    int e = gid / CP4;
    int q = gid % CP4;
    int si = sidx[e];
    int di = didx[e];
    float s = scale ? scale[si] : 1.f;
    const float4 v = *(const float4*)(src + (long long)si * C + q * 4);
    float* d = dst + (long long)di * C + q * 4;
    atomicAdd(d + 0, v.x * s);
    atomicAdd(d + 1, v.y * s);
    atomicAdd(d + 2, v.z * s);
    atomicAdd(d + 3, v.w * s);
}

// ---------------- epilogue 1: h = relu(h * Dinv[row] + b1[col]) ----------------
__global__ void epilogue1_kernel(float* __restrict__ h, const float* __restrict__ Dinv,
                                 const float* __restrict__ b1) {
    int i = blockIdx.x * blockDim.x + threadIdx.x;
    if (i < N_NODES * HID_CH) {
        int row = i / HID_CH;
        int col = i % HID_CH;
        float v = h[i] * Dinv[row] + b1[col];
        h[i] = v > 0.f ? v : 0.f;
    }
}

// ---------------- final: out = log_softmax(out2*Dinv + b2), one wave per row ----------------
__global__ void logsoftmax_kernel(const float* __restrict__ out2, const float* __restrict__ Dinv,
                                  const float* __restrict__ b2, float* __restrict__ out) {
    int row = blockIdx.x * (blockDim.x >> 6) + (threadIdx.x >> 6);
    int lane = threadIdx.x & 63;
    if (row >= N_NODES) return;
    float v = out2[(long long)row * OUT_CH + lane] * Dinv[row] + b2[lane];
    float m = v;
    #pragma unroll
    for (int off = 32; off >= 1; off >>= 1) m = fmaxf(m, __shfl_xor(m, off));
    float ex = expf(v - m);
    float s = ex;
    #pragma unroll
    for (int off = 32; off >= 1; off >>= 1) s += __shfl_xor(s, off);
    out[(long long)row * OUT_CH + lane] = v - m - logf(s);
}

extern "C" void kernel_launch(void* const* d_in, const int* in_sizes, int n_in,
                              void* d_out, int out_size, void* d_ws, size_t ws_size,
                              hipStream_t stream) {
    const float* x  = (const float*)d_in[0];
    const int*   ei = (const int*)d_in[1];     // [2, NNZ] int32
    const float* W1 = (const float*)d_in[2];
    const float* b1 = (const float*)d_in[3];
    const float* W2 = (const float*)d_in[4];
    const float* b2 = (const float*)d_in[5];
    float* out = (float*)d_out;

    const int* node_idx  = ei;
    const int* hedge_idx = ei + NNZ_;

    float* ws = (float*)d_ws;
    const size_t NA = (size_t)N_NODES * HID_CH;          // 12.8M floats
    float* regionA = ws;                                  // h1 -> out1/h2
    float* regionB = ws + NA;                             // m1 -> {g, m2, out2}
    float* g    = regionB;
    float* m2   = regionB + (size_t)N_NODES * OUT_CH;
    float* out2 = regionB + 2 * (size_t)N_NODES * OUT_CH;
    float* Dinv = ws + 2 * NA;                            // N_NODES floats
    float* Binv = Dinv + N_NODES;                         // N_HEDGES floats
    // total ws use: 2*12.8M + 0.1M floats ~= 103 MB

    // degrees
    hipMemsetAsync(Dinv, 0, (N_NODES + N_HEDGES) * sizeof(float), stream);
    degree_kernel<<<(NNZ_ + 255) / 256, 256, 0, stream>>>(node_idx, hedge_idx, Dinv, Binv);
    invert_kernel<<<(N_NODES + 255) / 256, 256, 0, stream>>>(Dinv, Binv);

    // layer 1: h1 = x @ W1
    gemm_kernel<<<dim3(HID_CH / 64, (N_NODES + 63) / 64), dim3(16, 16), 0, stream>>>(
        x, W1, regionA, N_NODES, HID_CH, IN_CH);

    // m1 = segsum(h1[node] -> hedge)
    hipMemsetAsync(regionB, 0, NA * sizeof(float), stream);
    scatter_kernel<HID_CH><<<(NNZ_ * (HID_CH / 4) + 255) / 256, 256, 0, stream>>>(
        regionA, regionB, node_idx, hedge_idx, nullptr);
    // out1 = segsum(m1[hedge]*Binv -> node)   (reuse regionA)
    hipMemsetAsync(regionA, 0, NA * sizeof(float), stream);
    scatter_kernel<HID_CH><<<(NNZ_ * (HID_CH / 4) + 255) / 256, 256, 0, stream>>>(
        regionB, regionA, hedge_idx, node_idx, Binv);
    // h2 = relu(out1*Dinv + b1)
    epilogue1_kernel<<<(int)((NA + 255) / 256), 256, 0, stream>>>(regionA, Dinv, b1);

    // layer 2: g = h2 @ W2
    gemm_kernel<<<dim3(OUT_CH / 64, (N_NODES + 63) / 64), dim3(16, 16), 0, stream>>>(
        regionA, W2, g, N_NODES, OUT_CH, HID_CH);

    // m2 = segsum(g[node] -> hedge)
    hipMemsetAsync(m2, 0, (size_t)N_HEDGES * OUT_CH * sizeof(float), stream);
    scatter_kernel<OUT_CH><<<(NNZ_ * (OUT_CH / 4) + 255) / 256, 256, 0, stream>>>(
        g, m2, node_idx, hedge_idx, nullptr);
    // out2 = segsum(m2[hedge]*Binv -> node)
    hipMemsetAsync(out2, 0, (size_t)N_NODES * OUT_CH * sizeof(float), stream);
    scatter_kernel<OUT_CH><<<(NNZ_ * (OUT_CH / 4) + 255) / 256, 256, 0, stream>>>(
        m2, out2, hedge_idx, node_idx, Binv);

    // out = log_softmax(out2*Dinv + b2)
    logsoftmax_kernel<<<(N_NODES + 3) / 4, 256, 0, stream>>>(out2, Dinv, b2, out);
}

// Round 2
// 1203.431 us; speedup vs baseline: 6.1001x; 6.1001x over previous
//
#include <hip/hip_runtime.h>
#include <math.h>

#define N_NODES  50000
#define N_HEDGES 50000
#define NNZ_     800000
#define IN_CH    512
#define HID_CH   256
#define OUT_CH   64

// ---------------- CSR build: histogram ----------------
__global__ void hist_kernel(const int* __restrict__ ni, const int* __restrict__ hi,
                            int* __restrict__ cntN, int* __restrict__ cntH) {
    int i = blockIdx.x * blockDim.x + threadIdx.x;
    if (i < NNZ_) {
        atomicAdd(&cntN[ni[i]], 1);
        atomicAdd(&cntH[hi[i]], 1);
    }
}

// ---------------- inverse degrees from counts ----------------
__global__ void inv_kernel(const int* __restrict__ cntN, const int* __restrict__ cntH,
                           float* __restrict__ Dinv, float* __restrict__ Binv) {
    int i = blockIdx.x * blockDim.x + threadIdx.x;
    if (i < N_NODES)  { int c = cntN[i]; Dinv[i] = c > 0 ? 1.f / (float)c : 0.f; }
    if (i < N_HEDGES) { int c = cntH[i]; Binv[i] = c > 0 ? 1.f / (float)c : 0.f; }
}

// ---------------- single-block exclusive scan (2 arrays via blockIdx) ----------------
__global__ void scan2_kernel(const int* __restrict__ cntA, int* __restrict__ offA,
                             const int* __restrict__ cntB, int* __restrict__ offB, int n) {
    const int* cnt = blockIdx.x ? cntB : cntA;
    int* off = blockIdx.x ? offB : offA;
    __shared__ int buf[256];
    __shared__ int carry;
    const int tid = threadIdx.x;
    if (tid == 0) carry = 0;
    __syncthreads();
    for (int base = 0; base < n; base += 256) {
        int i = base + tid;
        int v = (i < n) ? cnt[i] : 0;
        buf[tid] = v;
        __syncthreads();
        #pragma unroll
        for (int d = 1; d < 256; d <<= 1) {
            int t = (tid >= d) ? buf[tid - d] : 0;
            __syncthreads();
            buf[tid] += t;
            __syncthreads();
        }
        int excl = carry + buf[tid] - v;
        if (i < n) off[i] = excl;
        __syncthreads();                 // all reads of carry/buf done
        if (tid == 0) carry += buf[255];
        __syncthreads();                 // carry updated before next chunk
    }
    if (tid == 0) off[n] = carry;
}

// ---------------- CSR fill (order within segment arbitrary) ----------------
__global__ void fill_kernel(const int* __restrict__ ni, const int* __restrict__ hi,
                            const int* __restrict__ offN, const int* __restrict__ offH,
                            int* __restrict__ curN, int* __restrict__ curH,
                            int* __restrict__ colN, int* __restrict__ colH) {
    int i = blockIdx.x * blockDim.x + threadIdx.x;
    if (i >= NNZ_) return;
    int n = ni[i], h = hi[i];
    int pH = atomicAdd(&curH[h], 1);
    colH[offH[h] + pH] = n;
    int pN = atomicAdd(&curN[n], 1);
    colN[offN[n] + pN] = h;
}

// ---------------- fp32 tiled GEMM: C[M,N] = A[M,K] @ B[K,N] ----------------
__global__ void gemm_kernel(const float* __restrict__ A, const float* __restrict__ B,
                            float* __restrict__ C, int M, int N, int K) {
    __shared__ float As[16][64 + 1];
    __shared__ float Bs[16][64 + 1];
    const int tx = threadIdx.x;
    const int ty = threadIdx.y;
    const int tid = ty * 16 + tx;
    const int row0 = blockIdx.y * 64;
    const int col0 = blockIdx.x * 64;

    float acc[4][4] = {};

    for (int k0 = 0; k0 < K; k0 += 16) {
        #pragma unroll
        for (int i = tid; i < 64 * 16; i += 256) {
            int r = i >> 4, c = i & 15;
            int gr = row0 + r;
            As[c][r] = (gr < M) ? A[(long long)gr * K + k0 + c] : 0.f;
        }
        #pragma unroll
        for (int i = tid; i < 16 * 64; i += 256) {
            int r = i >> 6, c = i & 63;
            Bs[r][c] = B[(long long)(k0 + r) * N + col0 + c];
        }
        __syncthreads();
        #pragma unroll
        for (int k = 0; k < 16; ++k) {
            float a[4], b[4];
            #pragma unroll
            for (int i = 0; i < 4; ++i) a[i] = As[k][ty * 4 + i];
            #pragma unroll
            for (int j = 0; j < 4; ++j) b[j] = Bs[k][tx * 4 + j];
            #pragma unroll
            for (int i = 0; i < 4; ++i)
                #pragma unroll
                for (int j = 0; j < 4; ++j)
                    acc[i][j] += a[i] * b[j];
        }
        __syncthreads();
    }
    #pragma unroll
    for (int i = 0; i < 4; ++i) {
        int gr = row0 + ty * 4 + i;
        if (gr < M) {
            #pragma unroll
            for (int j = 0; j < 4; ++j)
                C[(long long)gr * N + col0 + tx * 4 + j] = acc[i][j];
        }
    }
}

// ---------------- gather segment-sum, 256 channels ----------------
// one wave per dst row; lane handles float4 at channel 4*lane.
// dst[row] = (sum_{j in seg} src[col[j]]) * scale[row]  (+bias, relu if EPI)
template <bool EPI>
__global__ void gather256_kernel(const float* __restrict__ src, float* __restrict__ dst,
                                 const int* __restrict__ off, const int* __restrict__ col,
                                 const float* __restrict__ scale,
                                 const float* __restrict__ bias, int nrows) {
    int row = blockIdx.x * (blockDim.x >> 6) + (threadIdx.x >> 6);
    if (row >= nrows) return;
    int lane = threadIdx.x & 63;
    int s = off[row], e = off[row + 1];
    float ax = 0.f, ay = 0.f, az = 0.f, aw = 0.f;
    int j = s;
    for (; j + 1 < e; j += 2) {
        int sr0 = col[j], sr1 = col[j + 1];
        const float4 v0 = *(const float4*)(src + (size_t)sr0 * HID_CH + (lane << 2));
        const float4 v1 = *(const float4*)(src + (size_t)sr1 * HID_CH + (lane << 2));
        ax += v0.x + v1.x; ay += v0.y + v1.y;
        az += v0.z + v1.z; aw += v0.w + v1.w;
    }
    if (j < e) {
        int sr = col[j];
        const float4 v = *(const float4*)(src + (size_t)sr * HID_CH + (lane << 2));
        ax += v.x; ay += v.y; az += v.z; aw += v.w;
    }
    float sc = scale[row];
    float4 r;
    r.x = ax * sc; r.y = ay * sc; r.z = az * sc; r.w = aw * sc;
    if (EPI) {
        const float4 b = *(const float4*)(bias + (lane << 2));
        r.x += b.x; r.y += b.y; r.z += b.z; r.w += b.w;
        r.x = fmaxf(r.x, 0.f); r.y = fmaxf(r.y, 0.f);
        r.z = fmaxf(r.z, 0.f); r.w = fmaxf(r.w, 0.f);
    }
    *(float4*)(dst + (size_t)row * HID_CH + (lane << 2)) = r;
}

// ---------------- gather segment-sum, 64 channels ----------------
// one wave per dst row; lane = channel. Optionally fused bias + log_softmax.
template <bool LSM>
__global__ void gather64_kernel(const float* __restrict__ src, float* __restrict__ dst,
                                const int* __restrict__ off, const int* __restrict__ col,
                                const float* __restrict__ scale,
                                const float* __restrict__ bias, int nrows) {
    int row = blockIdx.x * (blockDim.x >> 6) + (threadIdx.x >> 6);
    if (row >= nrows) return;
    int lane = threadIdx.x & 63;
    int s = off[row], e = off[row + 1];
    float acc = 0.f;
    int j = s;
    for (; j + 1 < e; j += 2) {
        int sr0 = col[j], sr1 = col[j + 1];
        acc += src[(size_t)sr0 * OUT_CH + lane] + src[(size_t)sr1 * OUT_CH + lane];
    }
    if (j < e) acc += src[(size_t)col[j] * OUT_CH + lane];
    float v = acc * scale[row];
    if (LSM) {
        v += bias[lane];
        float m = v;
        #pragma unroll
        for (int o = 32; o >= 1; o >>= 1) m = fmaxf(m, __shfl_xor(m, o));
        float ex = expf(v - m);
        float su = ex;
        #pragma unroll
        for (int o = 32; o >= 1; o >>= 1) su += __shfl_xor(su, o);
        v = v - m - logf(su);
    }
    dst[(size_t)row * OUT_CH + lane] = v;
}

extern "C" void kernel_launch(void* const* d_in, const int* in_sizes, int n_in,
                              void* d_out, int out_size, void* d_ws, size_t ws_size,
                              hipStream_t stream) {
    const float* x  = (const float*)d_in[0];
    const int*   ei = (const int*)d_in[1];     // [2, NNZ] int32
    const float* W1 = (const float*)d_in[2];
    const float* b1 = (const float*)d_in[3];
    const float* W2 = (const float*)d_in[4];
    const float* b2 = (const float*)d_in[5];
    float* out = (float*)d_out;

    const int* node_idx  = ei;
    const int* hedge_idx = ei + NNZ_;

    const size_t NA = (size_t)N_NODES * HID_CH;  // 12.8M floats
    float* regionA = (float*)d_ws;               // h1 -> h2
    float* regionB = regionA + NA;               // m1 -> {g, m2}
    float* Dinv = regionB + NA;
    float* Binv = Dinv + N_NODES;
    int* cntN = (int*)(Binv + N_HEDGES);         // also reused as cursors
    int* cntH = cntN + N_NODES;
    int* offN = cntH + N_HEDGES;                 // N_NODES+1
    int* offH = offN + N_NODES + 1;              // N_HEDGES+1
    int* colN = offH + N_HEDGES + 1;             // NNZ (hedge ids grouped by node)
    int* colH = colN + NNZ_;                     // NNZ (node ids grouped by hedge)

    // ---- CSR build + degrees ----
    hipMemsetAsync(cntN, 0, (N_NODES + N_HEDGES) * sizeof(int), stream);
    hist_kernel<<<(NNZ_ + 255) / 256, 256, 0, stream>>>(node_idx, hedge_idx, cntN, cntH);
    inv_kernel<<<(N_NODES + 255) / 256, 256, 0, stream>>>(cntN, cntH, Dinv, Binv);
    scan2_kernel<<<2, 256, 0, stream>>>(cntH, offH, cntN, offN, N_NODES);
    hipMemsetAsync(cntN, 0, (N_NODES + N_HEDGES) * sizeof(int), stream);
    fill_kernel<<<(NNZ_ + 255) / 256, 256, 0, stream>>>(
        node_idx, hedge_idx, offN, offH, cntN, cntH, colN, colH);

    // ---- layer 1 ----
    gemm_kernel<<<dim3(HID_CH / 64, (N_NODES + 63) / 64), dim3(16, 16), 0, stream>>>(
        x, W1, regionA, N_NODES, HID_CH, IN_CH);
    // m1 = (sum over nodes of h1) * Binv  (per hyperedge)
    gather256_kernel<false><<<(N_HEDGES + 3) / 4, 256, 0, stream>>>(
        regionA, regionB, offH, colH, Binv, nullptr, N_HEDGES);
    // h2 = relu((sum over hedges of m1) * Dinv + b1)  (per node)
    gather256_kernel<true><<<(N_NODES + 3) / 4, 256, 0, stream>>>(
        regionB, regionA, offN, colN, Dinv, b1, N_NODES);

    // ---- layer 2 ----
    float* g  = regionB;
    float* m2 = regionB + (size_t)N_NODES * OUT_CH;
    gemm_kernel<<<dim3(OUT_CH / 64, (N_NODES + 63) / 64), dim3(16, 16), 0, stream>>>(
        regionA, W2, g, N_NODES, OUT_CH, HID_CH);
    gather64_kernel<false><<<(N_HEDGES + 3) / 4, 256, 0, stream>>>(
        g, m2, offH, colH, Binv, nullptr, N_HEDGES);
    // fused: out = log_softmax((sum m2) * Dinv + b2)
    gather64_kernel<true><<<(N_NODES + 3) / 4, 256, 0, stream>>>(
        m2, out, offN, colN, Dinv, b2, N_NODES);
}

// Round 3
// 879.851 us; speedup vs baseline: 8.3435x; 1.3678x over previous
//
#include <hip/hip_runtime.h>
#include <math.h>

#define N_NODES  50000
#define N_HEDGES 50000
#define NNZ_     800000
#define IN_CH    512
#define HID_CH   256
#define OUT_CH   64
#define M_PAD    50048   // 391*128 rows of staging slack for global_load_lds

typedef __attribute__((ext_vector_type(8))) short bf16x8;
typedef __attribute__((ext_vector_type(4))) float f32x4;

__device__ __forceinline__ unsigned short f2bf(float f) {
    union { float f; unsigned u; } v; v.f = f;
    unsigned r = v.u + 0x7FFFu + ((v.u >> 16) & 1u);   // round-to-nearest-even
    return (unsigned short)(r >> 16);
}

#define GLL16(g, l)                                                            \
    __builtin_amdgcn_global_load_lds(                                          \
        (const __attribute__((address_space(1))) void*)(g),                    \
        (__attribute__((address_space(3))) void*)(l), 16, 0, 0)

// ---------------- CSR build: histogram ----------------
__global__ void hist_kernel(const int* __restrict__ ni, const int* __restrict__ hi,
                            int* __restrict__ cntN, int* __restrict__ cntH) {
    int i = blockIdx.x * blockDim.x + threadIdx.x;
    if (i < NNZ_) {
        atomicAdd(&cntN[ni[i]], 1);
        atomicAdd(&cntH[hi[i]], 1);
    }
}

__global__ void inv_kernel(const int* __restrict__ cntN, const int* __restrict__ cntH,
                           float* __restrict__ Dinv, float* __restrict__ Binv) {
    int i = blockIdx.x * blockDim.x + threadIdx.x;
    if (i < N_NODES)  { int c = cntN[i]; Dinv[i] = c > 0 ? 1.f / (float)c : 0.f; }
    if (i < N_HEDGES) { int c = cntH[i]; Binv[i] = c > 0 ? 1.f / (float)c : 0.f; }
}

// ---------------- single-block exclusive scan (2 arrays via blockIdx) ----------------
__global__ void scan2_kernel(const int* __restrict__ cntA, int* __restrict__ offA,
                             const int* __restrict__ cntB, int* __restrict__ offB, int n) {
    const int* cnt = blockIdx.x ? cntB : cntA;
    int* off = blockIdx.x ? offB : offA;
    __shared__ int buf[256];
    __shared__ int carry;
    const int tid = threadIdx.x;
    if (tid == 0) carry = 0;
    __syncthreads();
    for (int base = 0; base < n; base += 256) {
        int i = base + tid;
        int v = (i < n) ? cnt[i] : 0;
        buf[tid] = v;
        __syncthreads();
        #pragma unroll
        for (int d = 1; d < 256; d <<= 1) {
            int t = (tid >= d) ? buf[tid - d] : 0;
            __syncthreads();
            buf[tid] += t;
            __syncthreads();
        }
        int excl = carry + buf[tid] - v;
        if (i < n) off[i] = excl;
        __syncthreads();
        if (tid == 0) carry += buf[255];
        __syncthreads();
    }
    if (tid == 0) off[n] = carry;
}

// ---------------- CSR fill ----------------
__global__ void fill_kernel(const int* __restrict__ ni, const int* __restrict__ hi,
                            const int* __restrict__ offN, const int* __restrict__ offH,
                            int* __restrict__ curN, int* __restrict__ curH,
                            int* __restrict__ colN, int* __restrict__ colH) {
    int i = blockIdx.x * blockDim.x + threadIdx.x;
    if (i >= NNZ_) return;
    int n = ni[i], h = hi[i];
    int pH = atomicAdd(&curH[h], 1);
    colH[offH[h] + pH] = n;
    int pN = atomicAdd(&curN[n], 1);
    colN[offN[n] + pN] = h;
}

// ---------------- fp32 -> bf16 row-major convert (vectorized) ----------------
__global__ void cvt_bf16_kernel(const float* __restrict__ src,
                                unsigned short* __restrict__ dst, long n4) {
    long i = (long)blockIdx.x * blockDim.x + threadIdx.x;
    if (i >= n4) return;
    const float4 v = *(const float4*)(src + i * 4);
    ushort4 o;
    o.x = f2bf(v.x); o.y = f2bf(v.y); o.z = f2bf(v.z); o.w = f2bf(v.w);
    *(ushort4*)(dst + i * 4) = o;
}

// ---------------- W pack: Wp[kt][n][kk] (B-fragment order) ----------------
__global__ void pack_w_kernel(const float* __restrict__ W, unsigned short* __restrict__ Wp,
                              int K, int N) {
    int i = blockIdx.x * blockDim.x + threadIdx.x;
    if (i >= K * N) return;
    int kt = i / (N * 32);
    int r  = i % (N * 32);
    int n  = r >> 5;
    int kk = r & 31;
    Wp[i] = f2bf(W[(size_t)(kt * 32 + kk) * N + n]);
}

// ---------------- MFMA bf16 GEMM: C[M,N] = A[M,K] @ W[K,N] ----------------
// A: bf16 row-major (rows padded to M_PAD). Wp: packed [K/32][N][32] bf16.
// BM=128, BK=32, 256 threads = 4 waves (2x2), wave tile 64 x (BN/2).
template <int BN>
__global__ void mfma_gemm_kernel(const unsigned short* __restrict__ A,
                                 const unsigned short* __restrict__ Wp,
                                 float* __restrict__ C, int M, int N, int K) {
    constexpr int NT = BN / 32;            // n-tiles per wave
    __shared__ unsigned short As[128 * 32];
    __shared__ unsigned short Bs[BN * 32];

    const int tid  = threadIdx.x;
    const int wave = tid >> 6;
    const int lane = tid & 63;
    const int wr = wave >> 1;              // 0..1
    const int wc = wave & 1;               // 0..1
    const int quad = lane >> 4;
    const int l15  = lane & 15;
    const int row0 = blockIdx.y * 128;
    const int col0 = blockIdx.x * BN;

    // staging addresses (elements)
    const size_t a_g0   = (size_t)(row0 + wave * 16 + (lane >> 2)) * K + (lane & 3) * 8;
    const int    a_l0   = (wave * 16 + (lane >> 2)) * 32 + (lane & 3) * 8;
    const size_t b_gbase = ((size_t)col0 + wave * 16 + (lane >> 2)) * 32 + (lane & 3) * 8;
    const int    b_l0   = (wave * 16 + (lane >> 2)) * 32 + (lane & 3) * 8;

    f32x4 acc[4][NT];
    #pragma unroll
    for (int mt = 0; mt < 4; ++mt)
        #pragma unroll
        for (int nt = 0; nt < NT; ++nt)
            acc[mt][nt] = (f32x4)0.f;

    const int KT = K / 32;
    for (int kt = 0; kt < KT; ++kt) {
        __syncthreads();                   // protect previous tile's reads
        // stage A: 128x32 bf16 = 8 KB = 8 wave-loads (2 per wave)
        GLL16(A + a_g0 + (size_t)kt * 32, As + a_l0);
        GLL16(A + a_g0 + (size_t)(kt * 32) + (size_t)64 * K, As + a_l0 + 64 * 32);
        // stage B: BN x 32 bf16 (packed; contiguous 1 KB per wave-load)
        const size_t bk = (size_t)kt * N * 32;
        GLL16(Wp + bk + b_gbase, Bs + b_l0);
        if (BN == 128)
            GLL16(Wp + bk + b_gbase + 64 * 32, Bs + b_l0 + 64 * 32);
        __syncthreads();                   // compiler drains vmcnt before barrier

        bf16x8 af[4], bf[NT];
        #pragma unroll
        for (int mt = 0; mt < 4; ++mt)
            af[mt] = *(const bf16x8*)(As + (wr * 64 + mt * 16 + l15) * 32 + quad * 8);
        #pragma unroll
        for (int nt = 0; nt < NT; ++nt)
            bf[nt] = *(const bf16x8*)(Bs + (wc * (BN / 2) + nt * 16 + l15) * 32 + quad * 8);
        #pragma unroll
        for (int mt = 0; mt < 4; ++mt)
            #pragma unroll
            for (int nt = 0; nt < NT; ++nt)
                acc[mt][nt] = __builtin_amdgcn_mfma_f32_16x16x32_bf16(
                    af[mt], bf[nt], acc[mt][nt], 0, 0, 0);
    }

    // epilogue: C layout col=lane&15, row=quad*4+reg
    #pragma unroll
    for (int mt = 0; mt < 4; ++mt) {
        const int gr0 = row0 + wr * 64 + mt * 16 + quad * 4;
        #pragma unroll
        for (int nt = 0; nt < NT; ++nt) {
            const int gc = col0 + wc * (BN / 2) + nt * 16 + l15;
            #pragma unroll
            for (int r = 0; r < 4; ++r) {
                int gr = gr0 + r;
                if (gr < M) C[(size_t)gr * N + gc] = acc[mt][nt][r];
            }
        }
    }
}

// ---------------- gather segment-sum, 256 channels ----------------
// dst[row] = (sum src[col[j]]) * scale[row] (+bias, relu if EPI). BFOUT -> bf16 dst.
template <bool EPI, bool BFOUT>
__global__ void gather256_kernel(const float* __restrict__ src, void* __restrict__ dstv,
                                 const int* __restrict__ off, const int* __restrict__ col,
                                 const float* __restrict__ scale,
                                 const float* __restrict__ bias, int nrows) {
    int row = blockIdx.x * (blockDim.x >> 6) + (threadIdx.x >> 6);
    if (row >= nrows) return;
    int lane = threadIdx.x & 63;
    int s = off[row], e = off[row + 1];
    float ax = 0.f, ay = 0.f, az = 0.f, aw = 0.f;
    int j = s;
    for (; j + 1 < e; j += 2) {
        int sr0 = col[j], sr1 = col[j + 1];
        const float4 v0 = *(const float4*)(src + (size_t)sr0 * HID_CH + (lane << 2));
        const float4 v1 = *(const float4*)(src + (size_t)sr1 * HID_CH + (lane << 2));
        ax += v0.x + v1.x; ay += v0.y + v1.y;
        az += v0.z + v1.z; aw += v0.w + v1.w;
    }
    if (j < e) {
        int sr = col[j];
        const float4 v = *(const float4*)(src + (size_t)sr * HID_CH + (lane << 2));
        ax += v.x; ay += v.y; az += v.z; aw += v.w;
    }
    float sc = scale[row];
    float4 r;
    r.x = ax * sc; r.y = ay * sc; r.z = az * sc; r.w = aw * sc;
    if (EPI) {
        const float4 b = *(const float4*)(bias + (lane << 2));
        r.x = fmaxf(r.x + b.x, 0.f); r.y = fmaxf(r.y + b.y, 0.f);
        r.z = fmaxf(r.z + b.z, 0.f); r.w = fmaxf(r.w + b.w, 0.f);
    }
    if (BFOUT) {
        ushort4 o;
        o.x = f2bf(r.x); o.y = f2bf(r.y); o.z = f2bf(r.z); o.w = f2bf(r.w);
        *(ushort4*)((unsigned short*)dstv + (size_t)row * HID_CH + (lane << 2)) = o;
    } else {
        *(float4*)((float*)dstv + (size_t)row * HID_CH + (lane << 2)) = r;
    }
}

// ---------------- gather segment-sum, 64 channels (optional fused log_softmax) ----------
template <bool LSM>
__global__ void gather64_kernel(const float* __restrict__ src, float* __restrict__ dst,
                                const int* __restrict__ off, const int* __restrict__ col,
                                const float* __restrict__ scale,
                                const float* __restrict__ bias, int nrows) {
    int row = blockIdx.x * (blockDim.x >> 6) + (threadIdx.x >> 6);
    if (row >= nrows) return;
    int lane = threadIdx.x & 63;
    int s = off[row], e = off[row + 1];
    float acc = 0.f;
    int j = s;
    for (; j + 1 < e; j += 2) {
        int sr0 = col[j], sr1 = col[j + 1];
        acc += src[(size_t)sr0 * OUT_CH + lane] + src[(size_t)sr1 * OUT_CH + lane];
    }
    if (j < e) acc += src[(size_t)col[j] * OUT_CH + lane];
    float v = acc * scale[row];
    if (LSM) {
        v += bias[lane];
        float m = v;
        #pragma unroll
        for (int o = 32; o >= 1; o >>= 1) m = fmaxf(m, __shfl_xor(m, o));
        float ex = expf(v - m);
        float su = ex;
        #pragma unroll
        for (int o = 32; o >= 1; o >>= 1) su += __shfl_xor(su, o);
        v = v - m - logf(su);
    }
    dst[(size_t)row * OUT_CH + lane] = v;
}

extern "C" void kernel_launch(void* const* d_in, const int* in_sizes, int n_in,
                              void* d_out, int out_size, void* d_ws, size_t ws_size,
                              hipStream_t stream) {
    const float* x  = (const float*)d_in[0];
    const int*   ei = (const int*)d_in[1];
    const float* W1 = (const float*)d_in[2];
    const float* b1 = (const float*)d_in[3];
    const float* W2 = (const float*)d_in[4];
    const float* b2 = (const float*)d_in[5];
    float* out = (float*)d_out;

    const int* node_idx  = ei;
    const int* hedge_idx = ei + NNZ_;

    // ---- workspace layout (~110 MB, same budget as previous passing rounds) ----
    const size_t RCAP = (size_t)M_PAD * IN_CH / 2;   // 12,812,288 floats = 51.25 MB
    float* regionA = (float*)d_ws;                   // h1 fp32 | later: h2_bf + m2
    float* regionB = regionA + RCAP;                 // x_bf     | later: m1 fp32 | g fp32
    float* Dinv = regionB + RCAP;
    float* Binv = Dinv + N_NODES;
    int* cntN = (int*)(Binv + N_HEDGES);
    int* cntH = cntN + N_NODES;
    int* offN = cntH + N_HEDGES;                     // N_NODES+1
    int* offH = offN + N_NODES + 1;                  // N_HEDGES+1
    int* colN = offH + N_HEDGES + 1;                 // NNZ
    int* colH = colN + NNZ_;                         // NNZ
    unsigned short* Wp1 = (unsigned short*)(colH + NNZ_);   // 512*256
    unsigned short* Wp2 = Wp1 + IN_CH * HID_CH;             // 256*64

    unsigned short* x_bf  = (unsigned short*)regionB;            // M_PAD x 512
    float*          h1    = regionA;                             // 50000 x 256
    float*          m1    = regionB;                             // 50000 x 256
    unsigned short* h2_bf = (unsigned short*)regionA;            // M_PAD x 256
    float*          g     = regionB;                             // 50000 x 64
    float*          m2    = regionA + 7000000;                   // 50000 x 64 (past h2_bf)

    // ---- CSR build + degrees ----
    hipMemsetAsync(cntN, 0, (N_NODES + N_HEDGES) * sizeof(int), stream);
    hist_kernel<<<(NNZ_ + 255) / 256, 256, 0, stream>>>(node_idx, hedge_idx, cntN, cntH);
    inv_kernel<<<(N_NODES + 255) / 256, 256, 0, stream>>>(cntN, cntH, Dinv, Binv);
    scan2_kernel<<<2, 256, 0, stream>>>(cntH, offH, cntN, offN, N_NODES);
    hipMemsetAsync(cntN, 0, (N_NODES + N_HEDGES) * sizeof(int), stream);
    fill_kernel<<<(NNZ_ + 255) / 256, 256, 0, stream>>>(
        node_idx, hedge_idx, offN, offH, cntN, cntH, colN, colH);

    // ---- precision prep ----
    cvt_bf16_kernel<<<(N_NODES * IN_CH / 4 + 255) / 256, 256, 0, stream>>>(
        x, x_bf, (long)N_NODES * IN_CH / 4);
    pack_w_kernel<<<(IN_CH * HID_CH + 255) / 256, 256, 0, stream>>>(W1, Wp1, IN_CH, HID_CH);
    pack_w_kernel<<<(HID_CH * OUT_CH + 255) / 256, 256, 0, stream>>>(W2, Wp2, HID_CH, OUT_CH);

    // ---- layer 1: h1 = x @ W1 (MFMA bf16) ----
    mfma_gemm_kernel<128><<<dim3(HID_CH / 128, (N_NODES + 127) / 128), 256, 0, stream>>>(
        x_bf, Wp1, h1, N_NODES, HID_CH, IN_CH);
    gather256_kernel<false, false><<<(N_HEDGES + 3) / 4, 256, 0, stream>>>(
        h1, m1, offH, colH, Binv, nullptr, N_HEDGES);
    gather256_kernel<true, true><<<(N_NODES + 3) / 4, 256, 0, stream>>>(
        m1, h2_bf, offN, colN, Dinv, b1, N_NODES);

    // ---- layer 2: g = h2 @ W2 (MFMA bf16) ----
    mfma_gemm_kernel<64><<<dim3(OUT_CH / 64, (N_NODES + 127) / 128), 256, 0, stream>>>(
        h2_bf, Wp2, g, N_NODES, OUT_CH, HID_CH);
    gather64_kernel<false><<<(N_HEDGES + 3) / 4, 256, 0, stream>>>(
        g, m2, offH, colH, Binv, nullptr, N_HEDGES);
    gather64_kernel<true><<<(N_NODES + 3) / 4, 256, 0, stream>>>(
        m2, out, offN, colN, Dinv, b2, N_NODES);
}

// Round 4
// 748.740 us; speedup vs baseline: 9.8046x; 1.1751x over previous
//
#include <hip/hip_runtime.h>
#include <math.h>

#define N_NODES  50000
#define N_HEDGES 50000
#define NNZ_     800000
#define IN_CH    512
#define HID_CH   256
#define OUT_CH   64
#define M_PAD    50048   // 391*128 rows of staging slack for global_load_lds

typedef __attribute__((ext_vector_type(8))) short bf16x8;
typedef __attribute__((ext_vector_type(4))) float f32x4;

__device__ __forceinline__ unsigned short f2bf(float f) {
    union { float f; unsigned u; } v; v.f = f;
    unsigned r = v.u + 0x7FFFu + ((v.u >> 16) & 1u);   // round-to-nearest-even
    return (unsigned short)(r >> 16);
}

#define GLL16(g, l)                                                            \
    __builtin_amdgcn_global_load_lds(                                          \
        (const __attribute__((address_space(1))) void*)(g),                    \
        (__attribute__((address_space(3))) void*)(l), 16, 0, 0)

// ---------------- CSR build: histogram ----------------
__global__ void hist_kernel(const int* __restrict__ ni, const int* __restrict__ hi,
                            int* __restrict__ cntN, int* __restrict__ cntH) {
    int i = blockIdx.x * blockDim.x + threadIdx.x;
    if (i < NNZ_) {
        atomicAdd(&cntN[ni[i]], 1);
        atomicAdd(&cntH[hi[i]], 1);
    }
}

__global__ void inv_kernel(const int* __restrict__ cntN, const int* __restrict__ cntH,
                           float* __restrict__ Dinv, float* __restrict__ Binv) {
    int i = blockIdx.x * blockDim.x + threadIdx.x;
    if (i < N_NODES)  { int c = cntN[i]; Dinv[i] = c > 0 ? 1.f / (float)c : 0.f; }
    if (i < N_HEDGES) { int c = cntH[i]; Binv[i] = c > 0 ? 1.f / (float)c : 0.f; }
}

// ---------------- parallel exclusive scan: 1024 threads, chunk-per-thread ----------------
// grid.x selects which (cnt, off) pair; single block per array.
__global__ void scan_kernel(const int* __restrict__ cntA, int* __restrict__ offA,
                            const int* __restrict__ cntB, int* __restrict__ offB, int n) {
    const int* cnt = blockIdx.x ? cntB : cntA;
    int* off = blockIdx.x ? offB : offA;
    __shared__ int sums[1024];
    const int t = threadIdx.x;
    const int CHUNK = (n + 1023) / 1024;
    const int start = t * CHUNK;
    const int end   = min(start + CHUNK, n);
    int local = 0;
    for (int i = start; i < end; ++i) local += cnt[i];
    sums[t] = local;
    __syncthreads();
    #pragma unroll
    for (int d = 1; d < 1024; d <<= 1) {
        int v = (t >= d) ? sums[t - d] : 0;
        __syncthreads();
        sums[t] += v;
        __syncthreads();
    }
    int run = (t == 0) ? 0 : sums[t - 1];     // exclusive prefix of this chunk
    for (int i = start; i < end; ++i) {
        off[i] = run;
        run += cnt[i];
    }
    if (t == 1023) off[n] = sums[1023];
}

// ---------------- CSR fill ----------------
__global__ void fill_kernel(const int* __restrict__ ni, const int* __restrict__ hi,
                            const int* __restrict__ offN, const int* __restrict__ offH,
                            int* __restrict__ curN, int* __restrict__ curH,
                            int* __restrict__ colN, int* __restrict__ colH) {
    int i = blockIdx.x * blockDim.x + threadIdx.x;
    if (i >= NNZ_) return;
    int n = ni[i], h = hi[i];
    int pH = atomicAdd(&curH[h], 1);
    colH[offH[h] + pH] = n;
    int pN = atomicAdd(&curN[n], 1);
    colN[offN[n] + pN] = h;
}

// ---------------- fp32 -> bf16 row-major convert (vectorized) ----------------
__global__ void cvt_bf16_kernel(const float* __restrict__ src,
                                unsigned short* __restrict__ dst, long n4) {
    long i = (long)blockIdx.x * blockDim.x + threadIdx.x;
    if (i >= n4) return;
    const float4 v = *(const float4*)(src + i * 4);
    ushort4 o;
    o.x = f2bf(v.x); o.y = f2bf(v.y); o.z = f2bf(v.z); o.w = f2bf(v.w);
    *(ushort4*)(dst + i * 4) = o;
}

// ---------------- W pack: Wp[kt][n][kk] (B-fragment order) ----------------
__global__ void pack_w_kernel(const float* __restrict__ W, unsigned short* __restrict__ Wp,
                              int K, int N) {
    int i = blockIdx.x * blockDim.x + threadIdx.x;
    if (i >= K * N) return;
    int kt = i / (N * 32);
    int r  = i % (N * 32);
    int n  = r >> 5;
    int kk = r & 31;
    Wp[i] = f2bf(W[(size_t)(kt * 32 + kk) * N + n]);
}

// ---------------- MFMA bf16 GEMM: C[M,N] = A[M,K] @ W[K,N] ----------------
// A: bf16 row-major (rows padded to M_PAD). Wp: packed [K/32][N][32] bf16.
// BM=128, BK=32, 256 threads = 4 waves (2x2), wave tile 64 x (BN/2).
template <int BN>
__global__ void mfma_gemm_kernel(const unsigned short* __restrict__ A,
                                 const unsigned short* __restrict__ Wp,
                                 float* __restrict__ C, int M, int N, int K) {
    constexpr int NT = BN / 32;            // n-tiles per wave
    __shared__ unsigned short As[128 * 32];
    __shared__ unsigned short Bs[BN * 32];

    const int tid  = threadIdx.x;
    const int wave = tid >> 6;
    const int lane = tid & 63;
    const int wr = wave >> 1;              // 0..1
    const int wc = wave & 1;               // 0..1
    const int quad = lane >> 4;
    const int l15  = lane & 15;
    const int row0 = blockIdx.y * 128;
    const int col0 = blockIdx.x * BN;

    const size_t a_g0   = (size_t)(row0 + wave * 16 + (lane >> 2)) * K + (lane & 3) * 8;
    const int    a_l0   = (wave * 16 + (lane >> 2)) * 32 + (lane & 3) * 8;
    const size_t b_gbase = ((size_t)col0 + wave * 16 + (lane >> 2)) * 32 + (lane & 3) * 8;
    const int    b_l0   = (wave * 16 + (lane >> 2)) * 32 + (lane & 3) * 8;

    f32x4 acc[4][NT];
    #pragma unroll
    for (int mt = 0; mt < 4; ++mt)
        #pragma unroll
        for (int nt = 0; nt < NT; ++nt)
            acc[mt][nt] = (f32x4)0.f;

    const int KT = K / 32;
    for (int kt = 0; kt < KT; ++kt) {
        __syncthreads();
        GLL16(A + a_g0 + (size_t)kt * 32, As + a_l0);
        GLL16(A + a_g0 + (size_t)(kt * 32) + (size_t)64 * K, As + a_l0 + 64 * 32);
        const size_t bk = (size_t)kt * N * 32;
        GLL16(Wp + bk + b_gbase, Bs + b_l0);
        if (BN == 128)
            GLL16(Wp + bk + b_gbase + 64 * 32, Bs + b_l0 + 64 * 32);
        __syncthreads();

        bf16x8 af[4], bf[NT];
        #pragma unroll
        for (int mt = 0; mt < 4; ++mt)
            af[mt] = *(const bf16x8*)(As + (wr * 64 + mt * 16 + l15) * 32 + quad * 8);
        #pragma unroll
        for (int nt = 0; nt < NT; ++nt)
            bf[nt] = *(const bf16x8*)(Bs + (wc * (BN / 2) + nt * 16 + l15) * 32 + quad * 8);
        #pragma unroll
        for (int mt = 0; mt < 4; ++mt)
            #pragma unroll
            for (int nt = 0; nt < NT; ++nt)
                acc[mt][nt] = __builtin_amdgcn_mfma_f32_16x16x32_bf16(
                    af[mt], bf[nt], acc[mt][nt], 0, 0, 0);
    }

    #pragma unroll
    for (int mt = 0; mt < 4; ++mt) {
        const int gr0 = row0 + wr * 64 + mt * 16 + quad * 4;
        #pragma unroll
        for (int nt = 0; nt < NT; ++nt) {
            const int gc = col0 + wc * (BN / 2) + nt * 16 + l15;
            #pragma unroll
            for (int r = 0; r < 4; ++r) {
                int gr = gr0 + r;
                if (gr < M) C[(size_t)gr * N + gc] = acc[mt][nt][r];
            }
        }
    }
}

// ---------------- gather segment-sum, 256 channels ----------------
template <bool EPI, bool BFOUT>
__global__ void gather256_kernel(const float* __restrict__ src, void* __restrict__ dstv,
                                 const int* __restrict__ off, const int* __restrict__ col,
                                 const float* __restrict__ scale,
                                 const float* __restrict__ bias, int nrows) {
    int row = blockIdx.x * (blockDim.x >> 6) + (threadIdx.x >> 6);
    if (row >= nrows) return;
    int lane = threadIdx.x & 63;
    int s = off[row], e = off[row + 1];
    float ax = 0.f, ay = 0.f, az = 0.f, aw = 0.f;
    int j = s;
    for (; j + 1 < e; j += 2) {
        int sr0 = col[j], sr1 = col[j + 1];
        const float4 v0 = *(const float4*)(src + (size_t)sr0 * HID_CH + (lane << 2));
        const float4 v1 = *(const float4*)(src + (size_t)sr1 * HID_CH + (lane << 2));
        ax += v0.x + v1.x; ay += v0.y + v1.y;
        az += v0.z + v1.z; aw += v0.w + v1.w;
    }
    if (j < e) {
        int sr = col[j];
        const float4 v = *(const float4*)(src + (size_t)sr * HID_CH + (lane << 2));
        ax += v.x; ay += v.y; az += v.z; aw += v.w;
    }
    float sc = scale[row];
    float4 r;
    r.x = ax * sc; r.y = ay * sc; r.z = az * sc; r.w = aw * sc;
    if (EPI) {
        const float4 b = *(const float4*)(bias + (lane << 2));
        r.x = fmaxf(r.x + b.x, 0.f); r.y = fmaxf(r.y + b.y, 0.f);
        r.z = fmaxf(r.z + b.z, 0.f); r.w = fmaxf(r.w + b.w, 0.f);
    }
    if (BFOUT) {
        ushort4 o;
        o.x = f2bf(r.x); o.y = f2bf(r.y); o.z = f2bf(r.z); o.w = f2bf(r.w);
        *(ushort4*)((unsigned short*)dstv + (size_t)row * HID_CH + (lane << 2)) = o;
    } else {
        *(float4*)((float*)dstv + (size_t)row * HID_CH + (lane << 2)) = r;
    }
}

// ---------------- gather segment-sum, 64 channels (optional fused log_softmax) ----------
template <bool LSM>
__global__ void gather64_kernel(const float* __restrict__ src, float* __restrict__ dst,
                                const int* __restrict__ off, const int* __restrict__ col,
                                const float* __restrict__ scale,
                                const float* __restrict__ bias, int nrows) {
    int row = blockIdx.x * (blockDim.x >> 6) + (threadIdx.x >> 6);
    if (row >= nrows) return;
    int lane = threadIdx.x & 63;
    int s = off[row], e = off[row + 1];
    float acc = 0.f;
    int j = s;
    for (; j + 1 < e; j += 2) {
        int sr0 = col[j], sr1 = col[j + 1];
        acc += src[(size_t)sr0 * OUT_CH + lane] + src[(size_t)sr1 * OUT_CH + lane];
    }
    if (j < e) acc += src[(size_t)col[j] * OUT_CH + lane];
    float v = acc * scale[row];
    if (LSM) {
        v += bias[lane];
        float m = v;
        #pragma unroll
        for (int o = 32; o >= 1; o >>= 1) m = fmaxf(m, __shfl_xor(m, o));
        float ex = expf(v - m);
        float su = ex;
        #pragma unroll
        for (int o = 32; o >= 1; o >>= 1) su += __shfl_xor(su, o);
        v = v - m - logf(su);
    }
    dst[(size_t)row * OUT_CH + lane] = v;
}

extern "C" void kernel_launch(void* const* d_in, const int* in_sizes, int n_in,
                              void* d_out, int out_size, void* d_ws, size_t ws_size,
                              hipStream_t stream) {
    const float* x  = (const float*)d_in[0];
    const int*   ei = (const int*)d_in[1];
    const float* W1 = (const float*)d_in[2];
    const float* b1 = (const float*)d_in[3];
    const float* W2 = (const float*)d_in[4];
    const float* b2 = (const float*)d_in[5];
    float* out = (float*)d_out;

    const int* node_idx  = ei;
    const int* hedge_idx = ei + NNZ_;

    const size_t RCAP = (size_t)M_PAD * IN_CH / 2;   // 12,812,288 floats = 51.25 MB
    float* regionA = (float*)d_ws;
    float* regionB = regionA + RCAP;
    float* Dinv = regionB + RCAP;
    float* Binv = Dinv + N_NODES;
    int* cntN = (int*)(Binv + N_HEDGES);
    int* cntH = cntN + N_NODES;
    int* offN = cntH + N_HEDGES;
    int* offH = offN + N_NODES + 1;
    int* colN = offH + N_HEDGES + 1;
    int* colH = colN + NNZ_;
    unsigned short* Wp1 = (unsigned short*)(colH + NNZ_);
    unsigned short* Wp2 = Wp1 + IN_CH * HID_CH;

    unsigned short* x_bf  = (unsigned short*)regionB;
    float*          h1    = regionA;
    float*          m1    = regionB;
    unsigned short* h2_bf = (unsigned short*)regionA;
    float*          g     = regionB;
    float*          m2    = regionA + 7000000;

    // ---- CSR build + degrees ----
    hipMemsetAsync(cntN, 0, (N_NODES + N_HEDGES) * sizeof(int), stream);
    hist_kernel<<<(NNZ_ + 255) / 256, 256, 0, stream>>>(node_idx, hedge_idx, cntN, cntH);
    inv_kernel<<<(N_NODES + 255) / 256, 256, 0, stream>>>(cntN, cntH, Dinv, Binv);
    scan_kernel<<<2, 1024, 0, stream>>>(cntH, offH, cntN, offN, N_NODES);
    hipMemsetAsync(cntN, 0, (N_NODES + N_HEDGES) * sizeof(int), stream);
    fill_kernel<<<(NNZ_ + 255) / 256, 256, 0, stream>>>(
        node_idx, hedge_idx, offN, offH, cntN, cntH, colN, colH);

    // ---- precision prep ----
    cvt_bf16_kernel<<<(N_NODES * IN_CH / 4 + 255) / 256, 256, 0, stream>>>(
        x, x_bf, (long)N_NODES * IN_CH / 4);
    pack_w_kernel<<<(IN_CH * HID_CH + 255) / 256, 256, 0, stream>>>(W1, Wp1, IN_CH, HID_CH);
    pack_w_kernel<<<(HID_CH * OUT_CH + 255) / 256, 256, 0, stream>>>(W2, Wp2, HID_CH, OUT_CH);

    // ---- layer 1: h1 = x @ W1 (MFMA bf16) ----
    mfma_gemm_kernel<128><<<dim3(HID_CH / 128, (N_NODES + 127) / 128), 256, 0, stream>>>(
        x_bf, Wp1, h1, N_NODES, HID_CH, IN_CH);
    gather256_kernel<false, false><<<(N_HEDGES + 3) / 4, 256, 0, stream>>>(
        h1, m1, offH, colH, Binv, nullptr, N_HEDGES);
    gather256_kernel<true, true><<<(N_NODES + 3) / 4, 256, 0, stream>>>(
        m1, h2_bf, offN, colN, Dinv, b1, N_NODES);

    // ---- layer 2: g = h2 @ W2 (MFMA bf16) ----
    mfma_gemm_kernel<64><<<dim3(OUT_CH / 64, (N_NODES + 127) / 128), 256, 0, stream>>>(
        h2_bf, Wp2, g, N_NODES, OUT_CH, HID_CH);
    gather64_kernel<false><<<(N_HEDGES + 3) / 4, 256, 0, stream>>>(
        g, m2, offH, colH, Binv, nullptr, N_HEDGES);
    gather64_kernel<true><<<(N_NODES + 3) / 4, 256, 0, stream>>>(
        m2, out, offN, colN, Dinv, b2, N_NODES);
}

// Round 5
// 673.443 us; speedup vs baseline: 10.9008x; 1.1118x over previous
//
#include <hip/hip_runtime.h>
#include <math.h>

#define N_NODES  50000
#define N_HEDGES 50000
#define NNZ_     800000
#define IN_CH    512
#define HID_CH   256
#define OUT_CH   64
#define M_PAD    50048   // 391*128 rows of staging slack for global_load_lds

typedef __attribute__((ext_vector_type(8))) short bf16x8;
typedef __attribute__((ext_vector_type(4))) float f32x4;

__device__ __forceinline__ unsigned short f2bf(float f) {
    union { float f; unsigned u; } v; v.f = f;
    unsigned r = v.u + 0x7FFFu + ((v.u >> 16) & 1u);   // round-to-nearest-even
    return (unsigned short)(r >> 16);
}
__device__ __forceinline__ float bf2f(unsigned short u) {
    union { unsigned u; float f; } v; v.u = (unsigned)u << 16; return v.f;
}

#define GLL16(g, l)                                                            \
    __builtin_amdgcn_global_load_lds(                                          \
        (const __attribute__((address_space(1))) void*)(g),                    \
        (__attribute__((address_space(3))) void*)(l), 16, 0, 0)

// ---------------- CSR build: histogram ----------------
__global__ void hist_kernel(const int* __restrict__ ni, const int* __restrict__ hi,
                            int* __restrict__ cntN, int* __restrict__ cntH) {
    int i = blockIdx.x * blockDim.x + threadIdx.x;
    if (i < NNZ_) {
        atomicAdd(&cntN[ni[i]], 1);
        atomicAdd(&cntH[hi[i]], 1);
    }
}

__global__ void inv_kernel(const int* __restrict__ cntN, const int* __restrict__ cntH,
                           float* __restrict__ Dinv, float* __restrict__ Binv) {
    int i = blockIdx.x * blockDim.x + threadIdx.x;
    if (i < N_NODES)  { int c = cntN[i]; Dinv[i] = c > 0 ? 1.f / (float)c : 0.f; }
    if (i < N_HEDGES) { int c = cntH[i]; Binv[i] = c > 0 ? 1.f / (float)c : 0.f; }
}

// ---------------- parallel exclusive scan: 1024 threads, chunk-per-thread ----------------
__global__ void scan_kernel(const int* __restrict__ cntA, int* __restrict__ offA,
                            const int* __restrict__ cntB, int* __restrict__ offB, int n) {
    const int* cnt = blockIdx.x ? cntB : cntA;
    int* off = blockIdx.x ? offB : offA;
    __shared__ int sums[1024];
    const int t = threadIdx.x;
    const int CHUNK = (n + 1023) / 1024;
    const int start = t * CHUNK;
    const int end   = min(start + CHUNK, n);
    int local = 0;
    for (int i = start; i < end; ++i) local += cnt[i];
    sums[t] = local;
    __syncthreads();
    #pragma unroll
    for (int d = 1; d < 1024; d <<= 1) {
        int v = (t >= d) ? sums[t - d] : 0;
        __syncthreads();
        sums[t] += v;
        __syncthreads();
    }
    int run = (t == 0) ? 0 : sums[t - 1];
    for (int i = start; i < end; ++i) {
        off[i] = run;
        run += cnt[i];
    }
    if (t == 1023) off[n] = sums[1023];
}

// ---------------- CSR fill ----------------
__global__ void fill_kernel(const int* __restrict__ ni, const int* __restrict__ hi,
                            const int* __restrict__ offN, const int* __restrict__ offH,
                            int* __restrict__ curN, int* __restrict__ curH,
                            int* __restrict__ colN, int* __restrict__ colH) {
    int i = blockIdx.x * blockDim.x + threadIdx.x;
    if (i >= NNZ_) return;
    int n = ni[i], h = hi[i];
    int pH = atomicAdd(&curH[h], 1);
    colH[offH[h] + pH] = n;
    int pN = atomicAdd(&curN[n], 1);
    colN[offN[n] + pN] = h;
}

// ---------------- fp32 -> bf16 row-major convert (vectorized) ----------------
__global__ void cvt_bf16_kernel(const float* __restrict__ src,
                                unsigned short* __restrict__ dst, long n4) {
    long i = (long)blockIdx.x * blockDim.x + threadIdx.x;
    if (i >= n4) return;
    const float4 v = *(const float4*)(src + i * 4);
    ushort4 o;
    o.x = f2bf(v.x); o.y = f2bf(v.y); o.z = f2bf(v.z); o.w = f2bf(v.w);
    *(ushort4*)(dst + i * 4) = o;
}

// ---------------- W pack: Wp[kt][n][kk] (B-fragment order) ----------------
__global__ void pack_w_kernel(const float* __restrict__ W, unsigned short* __restrict__ Wp,
                              int K, int N) {
    int i = blockIdx.x * blockDim.x + threadIdx.x;
    if (i >= K * N) return;
    int kt = i / (N * 32);
    int r  = i % (N * 32);
    int n  = r >> 5;
    int kk = r & 31;
    Wp[i] = f2bf(W[(size_t)(kt * 32 + kk) * N + n]);
}

// ---------------- MFMA bf16 GEMM: C[M,N] = A[M,K] @ W[K,N], bf16 output -----------
// A: bf16 row-major (rows padded to M_PAD). Wp: packed [K/32][N][32] bf16.
// BM=128, BK=32, 256 threads = 4 waves (2x2), wave tile 64 x (BN/2).
template <int BN>
__global__ void mfma_gemm_kernel(const unsigned short* __restrict__ A,
                                 const unsigned short* __restrict__ Wp,
                                 unsigned short* __restrict__ C, int M, int N, int K) {
    constexpr int NT = BN / 32;
    __shared__ unsigned short As[128 * 32];
    __shared__ unsigned short Bs[BN * 32];

    const int tid  = threadIdx.x;
    const int wave = tid >> 6;
    const int lane = tid & 63;
    const int wr = wave >> 1;
    const int wc = wave & 1;
    const int quad = lane >> 4;
    const int l15  = lane & 15;
    const int row0 = blockIdx.y * 128;
    const int col0 = blockIdx.x * BN;

    const size_t a_g0   = (size_t)(row0 + wave * 16 + (lane >> 2)) * K + (lane & 3) * 8;
    const int    a_l0   = (wave * 16 + (lane >> 2)) * 32 + (lane & 3) * 8;
    const size_t b_gbase = ((size_t)col0 + wave * 16 + (lane >> 2)) * 32 + (lane & 3) * 8;
    const int    b_l0   = (wave * 16 + (lane >> 2)) * 32 + (lane & 3) * 8;

    f32x4 acc[4][NT];
    #pragma unroll
    for (int mt = 0; mt < 4; ++mt)
        #pragma unroll
        for (int nt = 0; nt < NT; ++nt)
            acc[mt][nt] = (f32x4)0.f;

    const int KT = K / 32;
    for (int kt = 0; kt < KT; ++kt) {
        __syncthreads();
        GLL16(A + a_g0 + (size_t)kt * 32, As + a_l0);
        GLL16(A + a_g0 + (size_t)(kt * 32) + (size_t)64 * K, As + a_l0 + 64 * 32);
        const size_t bk = (size_t)kt * N * 32;
        GLL16(Wp + bk + b_gbase, Bs + b_l0);
        if (BN == 128)
            GLL16(Wp + bk + b_gbase + 64 * 32, Bs + b_l0 + 64 * 32);
        __syncthreads();

        bf16x8 af[4], bf[NT];
        #pragma unroll
        for (int mt = 0; mt < 4; ++mt)
            af[mt] = *(const bf16x8*)(As + (wr * 64 + mt * 16 + l15) * 32 + quad * 8);
        #pragma unroll
        for (int nt = 0; nt < NT; ++nt)
            bf[nt] = *(const bf16x8*)(Bs + (wc * (BN / 2) + nt * 16 + l15) * 32 + quad * 8);
        #pragma unroll
        for (int mt = 0; mt < 4; ++mt)
            #pragma unroll
            for (int nt = 0; nt < NT; ++nt)
                acc[mt][nt] = __builtin_amdgcn_mfma_f32_16x16x32_bf16(
                    af[mt], bf[nt], acc[mt][nt], 0, 0, 0);
    }

    // epilogue: C layout col=lane&15, row=quad*4+reg; emit bf16
    #pragma unroll
    for (int mt = 0; mt < 4; ++mt) {
        const int gr0 = row0 + wr * 64 + mt * 16 + quad * 4;
        #pragma unroll
        for (int nt = 0; nt < NT; ++nt) {
            const int gc = col0 + wc * (BN / 2) + nt * 16 + l15;
            #pragma unroll
            for (int r = 0; r < 4; ++r) {
                int gr = gr0 + r;
                if (gr < M) C[(size_t)gr * N + gc] = f2bf(acc[mt][nt][r]);
            }
        }
    }
}

// ---------------- gather segment-sum, 256 channels, bf16 in / bf16 out -----------
// dst[row] = (sum src[col[j]]) * scale[row] (+bias, relu if EPI)
template <bool EPI>
__global__ void gather256_kernel(const unsigned short* __restrict__ src,
                                 unsigned short* __restrict__ dst,
                                 const int* __restrict__ off, const int* __restrict__ col,
                                 const float* __restrict__ scale,
                                 const float* __restrict__ bias, int nrows) {
    int row = blockIdx.x * (blockDim.x >> 6) + (threadIdx.x >> 6);
    if (row >= nrows) return;
    int lane = threadIdx.x & 63;
    int s = off[row], e = off[row + 1];
    float ax = 0.f, ay = 0.f, az = 0.f, aw = 0.f;
    int j = s;
    for (; j + 1 < e; j += 2) {
        int sr0 = col[j], sr1 = col[j + 1];
        const ushort4 u0 = *(const ushort4*)(src + (size_t)sr0 * HID_CH + (lane << 2));
        const ushort4 u1 = *(const ushort4*)(src + (size_t)sr1 * HID_CH + (lane << 2));
        ax += bf2f(u0.x) + bf2f(u1.x); ay += bf2f(u0.y) + bf2f(u1.y);
        az += bf2f(u0.z) + bf2f(u1.z); aw += bf2f(u0.w) + bf2f(u1.w);
    }
    if (j < e) {
        const ushort4 u = *(const ushort4*)(src + (size_t)col[j] * HID_CH + (lane << 2));
        ax += bf2f(u.x); ay += bf2f(u.y); az += bf2f(u.z); aw += bf2f(u.w);
    }
    float sc = scale[row];
    float rx = ax * sc, ry = ay * sc, rz = az * sc, rw = aw * sc;
    if (EPI) {
        const float4 b = *(const float4*)(bias + (lane << 2));
        rx = fmaxf(rx + b.x, 0.f); ry = fmaxf(ry + b.y, 0.f);
        rz = fmaxf(rz + b.z, 0.f); rw = fmaxf(rw + b.w, 0.f);
    }
    ushort4 o;
    o.x = f2bf(rx); o.y = f2bf(ry); o.z = f2bf(rz); o.w = f2bf(rw);
    *(ushort4*)(dst + (size_t)row * HID_CH + (lane << 2)) = o;
}

// ---------------- gather segment-sum, 64 channels, bf16 in ----------------
// LSM=false: bf16 out.  LSM=true: fused bias+log_softmax, fp32 out.
template <bool LSM>
__global__ void gather64_kernel(const unsigned short* __restrict__ src, void* __restrict__ dstv,
                                const int* __restrict__ off, const int* __restrict__ col,
                                const float* __restrict__ scale,
                                const float* __restrict__ bias, int nrows) {
    int row = blockIdx.x * (blockDim.x >> 6) + (threadIdx.x >> 6);
    if (row >= nrows) return;
    int lane = threadIdx.x & 63;
    int s = off[row], e = off[row + 1];
    float acc = 0.f;
    int j = s;
    for (; j + 1 < e; j += 2) {
        int sr0 = col[j], sr1 = col[j + 1];
        acc += bf2f(src[(size_t)sr0 * OUT_CH + lane]) + bf2f(src[(size_t)sr1 * OUT_CH + lane]);
    }
    if (j < e) acc += bf2f(src[(size_t)col[j] * OUT_CH + lane]);
    float v = acc * scale[row];
    if (LSM) {
        v += bias[lane];
        float m = v;
        #pragma unroll
        for (int o = 32; o >= 1; o >>= 1) m = fmaxf(m, __shfl_xor(m, o));
        float ex = expf(v - m);
        float su = ex;
        #pragma unroll
        for (int o = 32; o >= 1; o >>= 1) su += __shfl_xor(su, o);
        ((float*)dstv)[(size_t)row * OUT_CH + lane] = v - m - logf(su);
    } else {
        ((unsigned short*)dstv)[(size_t)row * OUT_CH + lane] = f2bf(v);
    }
}

extern "C" void kernel_launch(void* const* d_in, const int* in_sizes, int n_in,
                              void* d_out, int out_size, void* d_ws, size_t ws_size,
                              hipStream_t stream) {
    const float* x  = (const float*)d_in[0];
    const int*   ei = (const int*)d_in[1];
    const float* W1 = (const float*)d_in[2];
    const float* b1 = (const float*)d_in[3];
    const float* W2 = (const float*)d_in[4];
    const float* b2 = (const float*)d_in[5];
    float* out = (float*)d_out;

    const int* node_idx  = ei;
    const int* hedge_idx = ei + NNZ_;

    const size_t RCAP = (size_t)M_PAD * IN_CH / 2;   // floats; 51.25 MB per region
    float* regionA = (float*)d_ws;
    float* regionB = regionA + RCAP;
    float* Dinv = regionB + RCAP;
    float* Binv = Dinv + N_NODES;
    int* cntN = (int*)(Binv + N_HEDGES);
    int* cntH = cntN + N_NODES;
    int* offN = cntH + N_HEDGES;
    int* offH = offN + N_NODES + 1;
    int* colN = offH + N_HEDGES + 1;
    int* colH = colN + NNZ_;
    unsigned short* Wp1 = (unsigned short*)(colH + NNZ_);
    unsigned short* Wp2 = Wp1 + IN_CH * HID_CH;

    unsigned short* x_bf  = (unsigned short*)regionB;            // M_PAD x 512
    unsigned short* h1_bf = (unsigned short*)regionA;            // M_PAD x 256
    unsigned short* m1_bf = (unsigned short*)regionB;            // 50000 x 256 (x dead)
    unsigned short* h2_bf = (unsigned short*)regionA;            // M_PAD x 256 (h1 dead)
    unsigned short* g_bf  = (unsigned short*)regionB;            // 50000 x 64 (m1 dead)
    unsigned short* m2_bf = (unsigned short*)regionB + (size_t)M_PAD * OUT_CH; // 50000 x 64

    // ---- CSR build + degrees ----
    hipMemsetAsync(cntN, 0, (N_NODES + N_HEDGES) * sizeof(int), stream);
    hist_kernel<<<(NNZ_ + 255) / 256, 256, 0, stream>>>(node_idx, hedge_idx, cntN, cntH);
    inv_kernel<<<(N_NODES + 255) / 256, 256, 0, stream>>>(cntN, cntH, Dinv, Binv);
    scan_kernel<<<2, 1024, 0, stream>>>(cntH, offH, cntN, offN, N_NODES);
    hipMemsetAsync(cntN, 0, (N_NODES + N_HEDGES) * sizeof(int), stream);
    fill_kernel<<<(NNZ_ + 255) / 256, 256, 0, stream>>>(
        node_idx, hedge_idx, offN, offH, cntN, cntH, colN, colH);

    // ---- precision prep ----
    cvt_bf16_kernel<<<(N_NODES * IN_CH / 4 + 255) / 256, 256, 0, stream>>>(
        x, x_bf, (long)N_NODES * IN_CH / 4);
    pack_w_kernel<<<(IN_CH * HID_CH + 255) / 256, 256, 0, stream>>>(W1, Wp1, IN_CH, HID_CH);
    pack_w_kernel<<<(HID_CH * OUT_CH + 255) / 256, 256, 0, stream>>>(W2, Wp2, HID_CH, OUT_CH);

    // ---- layer 1: h1 = x @ W1 (MFMA bf16) ----
    mfma_gemm_kernel<128><<<dim3(HID_CH / 128, (N_NODES + 127) / 128), 256, 0, stream>>>(
        x_bf, Wp1, h1_bf, N_NODES, HID_CH, IN_CH);
    gather256_kernel<false><<<(N_HEDGES + 3) / 4, 256, 0, stream>>>(
        h1_bf, m1_bf, offH, colH, Binv, nullptr, N_HEDGES);
    gather256_kernel<true><<<(N_NODES + 3) / 4, 256, 0, stream>>>(
        m1_bf, h2_bf, offN, colN, Dinv, b1, N_NODES);

    // ---- layer 2: g = h2 @ W2 (MFMA bf16) ----
    mfma_gemm_kernel<64><<<dim3(OUT_CH / 64, (N_NODES + 127) / 128), 256, 0, stream>>>(
        h2_bf, Wp2, g_bf, N_NODES, OUT_CH, HID_CH);
    gather64_kernel<false><<<(N_HEDGES + 3) / 4, 256, 0, stream>>>(
        g_bf, m2_bf, offH, colH, Binv, nullptr, N_HEDGES);
    gather64_kernel<true><<<(N_NODES + 3) / 4, 256, 0, stream>>>(
        m2_bf, out, offN, colN, Dinv, b2, N_NODES);
}

// Round 6
// 577.429 us; speedup vs baseline: 12.7134x; 1.1663x over previous
//
#include <hip/hip_runtime.h>
#include <math.h>

#define N_NODES  50000
#define N_HEDGES 50000
#define NNZ_     800000
#define IN_CH    512
#define HID_CH   256
#define OUT_CH   64
#define M_PAD    50048   // 391*128 rows of staging slack for global_load_lds
#define NBK      391     // buckets of 128 ids: ceil(50000/128)

typedef __attribute__((ext_vector_type(8))) short bf16x8;
typedef __attribute__((ext_vector_type(4))) float f32x4;

__device__ __forceinline__ unsigned short f2bf(float f) {
    union { float f; unsigned u; } v; v.f = f;
    unsigned r = v.u + 0x7FFFu + ((v.u >> 16) & 1u);   // round-to-nearest-even
    return (unsigned short)(r >> 16);
}
__device__ __forceinline__ float bf2f(unsigned short u) {
    union { unsigned u; float f; } v; v.u = (unsigned)u << 16; return v.f;
}

#define GLL16(g, l)                                                            \
    __builtin_amdgcn_global_load_lds(                                          \
        (const __attribute__((address_space(1))) void*)(g),                    \
        (__attribute__((address_space(3))) void*)(l), 16, 0, 0)

// ---------------- bucket histogram (both sides), LDS-aggregated ----------------
__global__ void bhist_kernel(const int* __restrict__ ni, const int* __restrict__ hi,
                             int* __restrict__ bcntN, int* __restrict__ bcntH) {
    __shared__ int lh[NBK], ln[NBK];
    for (int t = threadIdx.x; t < NBK; t += blockDim.x) { lh[t] = 0; ln[t] = 0; }
    __syncthreads();
    const int stride = gridDim.x * blockDim.x;           // in int4 units
    for (int i4 = blockIdx.x * blockDim.x + threadIdx.x; i4 < NNZ_ / 4; i4 += stride) {
        const int4 nv = *(const int4*)(ni + i4 * 4);
        const int4 hv = *(const int4*)(hi + i4 * 4);
        atomicAdd(&ln[nv.x >> 7], 1); atomicAdd(&ln[nv.y >> 7], 1);
        atomicAdd(&ln[nv.z >> 7], 1); atomicAdd(&ln[nv.w >> 7], 1);
        atomicAdd(&lh[hv.x >> 7], 1); atomicAdd(&lh[hv.y >> 7], 1);
        atomicAdd(&lh[hv.z >> 7], 1); atomicAdd(&lh[hv.w >> 7], 1);
    }
    __syncthreads();
    for (int t = threadIdx.x; t < NBK; t += blockDim.x) {
        if (ln[t]) atomicAdd(&bcntN[t], ln[t]);
        if (lh[t]) atomicAdd(&bcntH[t], lh[t]);
    }
}

// ---------------- parallel exclusive scan: 1024 threads, chunk-per-thread ----------------
__global__ void scan_kernel(const int* __restrict__ cntA, int* __restrict__ offA,
                            const int* __restrict__ cntB, int* __restrict__ offB, int n) {
    const int* cnt = blockIdx.x ? cntB : cntA;
    int* off = blockIdx.x ? offB : offA;
    __shared__ int sums[1024];
    const int t = threadIdx.x;
    const int CHUNK = (n + 1023) / 1024;
    const int start = t * CHUNK;
    const int end   = min(start + CHUNK, n);
    int local = 0;
    for (int i = start; i < end; ++i) local += cnt[i];
    sums[t] = local;
    __syncthreads();
    #pragma unroll
    for (int d = 1; d < 1024; d <<= 1) {
        int v = (t >= d) ? sums[t - d] : 0;
        __syncthreads();
        sums[t] += v;
        __syncthreads();
    }
    int run = (t == 0) ? 0 : sums[t - 1];
    for (int i = start; i < end; ++i) {
        off[i] = run;
        run += cnt[i];
    }
    if (t == 1023) off[n] = sums[1023];
}

// ---------------- bin: scatter packed records into bucket slices ----------------
// record = (id & 127) << 16 | other_id   (both ids < 65536)
// bcur*: on entry exclusive bucket offsets; on exit inclusive bucket ends.
__global__ void bin_kernel(const int* __restrict__ ni, const int* __restrict__ hi,
                           int* __restrict__ bcurN, int* __restrict__ bcurH,
                           unsigned* __restrict__ recN, unsigned* __restrict__ recH) {
    __shared__ int cH[NBK], cN[NBK], bH[NBK], bN[NBK];
    for (int t = threadIdx.x; t < NBK; t += blockDim.x) { cH[t] = 0; cN[t] = 0; }
    __syncthreads();
    const int gid = blockIdx.x * blockDim.x + threadIdx.x;
    const int i0 = gid * 4;                  // NNZ_ divisible by 4; grid covers all
    int4 nv, hv;
    const bool act = (i0 < NNZ_);
    if (act) {
        nv = *(const int4*)(ni + i0);
        hv = *(const int4*)(hi + i0);
        atomicAdd(&cN[nv.x >> 7], 1); atomicAdd(&cN[nv.y >> 7], 1);
        atomicAdd(&cN[nv.z >> 7], 1); atomicAdd(&cN[nv.w >> 7], 1);
        atomicAdd(&cH[hv.x >> 7], 1); atomicAdd(&cH[hv.y >> 7], 1);
        atomicAdd(&cH[hv.z >> 7], 1); atomicAdd(&cH[hv.w >> 7], 1);
    }
    __syncthreads();
    for (int t = threadIdx.x; t < NBK; t += blockDim.x) {
        bH[t] = cH[t] ? atomicAdd(&bcurH[t], cH[t]) : 0;
        bN[t] = cN[t] ? atomicAdd(&bcurN[t], cN[t]) : 0;
    }
    __syncthreads();
    for (int t = threadIdx.x; t < NBK; t += blockDim.x) { cH[t] = bH[t]; cN[t] = bN[t]; }
    __syncthreads();
    if (act) {
        int nn[4] = {nv.x, nv.y, nv.z, nv.w};
        int hh[4] = {hv.x, hv.y, hv.z, hv.w};
        #pragma unroll
        for (int k = 0; k < 4; ++k) {
            int p = atomicAdd(&cH[hh[k] >> 7], 1);
            recH[p] = ((unsigned)(hh[k] & 127) << 16) | (unsigned)nn[k];
            p = atomicAdd(&cN[nn[k] >> 7], 1);
            recN[p] = ((unsigned)(nn[k] & 127) << 16) | (unsigned)hh[k];
        }
    }
}

// ---------------- fine counts per id from binned records (no global atomics) --------
__global__ void fcnt_kernel(const int* __restrict__ bcurH, const unsigned* __restrict__ recH,
                            const int* __restrict__ bcurN, const unsigned* __restrict__ recN,
                            int* __restrict__ cntH, int* __restrict__ cntN) {
    int b = blockIdx.x;
    const int* bcur; const unsigned* rec; int* cnt;
    if (b < NBK) { bcur = bcurH; rec = recH; cnt = cntH; }
    else         { b -= NBK; bcur = bcurN; rec = recN; cnt = cntN; }
    __shared__ int lc[128];
    if (threadIdx.x < 128) lc[threadIdx.x] = 0;
    __syncthreads();
    const int s = b ? bcur[b - 1] : 0;
    const int e = bcur[b];
    for (int i = s + threadIdx.x; i < e; i += blockDim.x)
        atomicAdd(&lc[rec[i] >> 16], 1);
    __syncthreads();
    const int id = b * 128 + threadIdx.x;
    if (threadIdx.x < 128 && id < N_NODES) cnt[id] = lc[threadIdx.x];
}

// ---------------- inverse degrees ----------------
__global__ void inv_kernel(const int* __restrict__ cntN, const int* __restrict__ cntH,
                           float* __restrict__ Dinv, float* __restrict__ Binv) {
    int i = blockIdx.x * blockDim.x + threadIdx.x;
    if (i < N_NODES)  { int c = cntN[i]; Dinv[i] = c > 0 ? 1.f / (float)c : 0.f; }
    if (i < N_HEDGES) { int c = cntH[i]; Binv[i] = c > 0 ? 1.f / (float)c : 0.f; }
}

// ---------------- CSR fill from binned records (bucket-local writes) ----------------
__global__ void fillcsr_kernel(const int* __restrict__ bcurH, const unsigned* __restrict__ recH,
                               const int* __restrict__ offH, int* __restrict__ colH,
                               const int* __restrict__ bcurN, const unsigned* __restrict__ recN,
                               const int* __restrict__ offN, int* __restrict__ colN) {
    int b = blockIdx.x;
    const int* bcur; const unsigned* rec; const int* off; int* col;
    if (b < NBK) { bcur = bcurH; rec = recH; off = offH; col = colH; }
    else         { b -= NBK; bcur = bcurN; rec = recN; off = offN; col = colN; }
    __shared__ int cur[128];
    const int id = b * 128 + threadIdx.x;
    if (threadIdx.x < 128) cur[threadIdx.x] = (id < N_NODES) ? off[id] : 0;
    __syncthreads();
    const int s = b ? bcur[b - 1] : 0;
    const int e = bcur[b];
    for (int i = s + threadIdx.x; i < e; i += blockDim.x) {
        const unsigned r = rec[i];
        const int p = atomicAdd(&cur[r >> 16], 1);
        col[p] = (int)(r & 0xFFFFu);
    }
}

// ---------------- fp32 -> bf16 row-major convert (vectorized) ----------------
__global__ void cvt_bf16_kernel(const float* __restrict__ src,
                                unsigned short* __restrict__ dst, long n4) {
    long i = (long)blockIdx.x * blockDim.x + threadIdx.x;
    if (i >= n4) return;
    const float4 v = *(const float4*)(src + i * 4);
    ushort4 o;
    o.x = f2bf(v.x); o.y = f2bf(v.y); o.z = f2bf(v.z); o.w = f2bf(v.w);
    *(ushort4*)(dst + i * 4) = o;
}

// ---------------- W pack: Wp[kt][n][kk] (B-fragment order) ----------------
__global__ void pack_w_kernel(const float* __restrict__ W, unsigned short* __restrict__ Wp,
                              int K, int N) {
    int i = blockIdx.x * blockDim.x + threadIdx.x;
    if (i >= K * N) return;
    int kt = i / (N * 32);
    int r  = i % (N * 32);
    int n  = r >> 5;
    int kk = r & 31;
    Wp[i] = f2bf(W[(size_t)(kt * 32 + kk) * N + n]);
}

// ---------------- MFMA bf16 GEMM: C[M,N] = A[M,K] @ W[K,N], bf16 output -----------
template <int BN>
__global__ void mfma_gemm_kernel(const unsigned short* __restrict__ A,
                                 const unsigned short* __restrict__ Wp,
                                 unsigned short* __restrict__ C, int M, int N, int K) {
    constexpr int NT = BN / 32;
    __shared__ unsigned short As[128 * 32];
    __shared__ unsigned short Bs[BN * 32];

    const int tid  = threadIdx.x;
    const int wave = tid >> 6;
    const int lane = tid & 63;
    const int wr = wave >> 1;
    const int wc = wave & 1;
    const int quad = lane >> 4;
    const int l15  = lane & 15;
    const int row0 = blockIdx.y * 128;
    const int col0 = blockIdx.x * BN;

    const size_t a_g0   = (size_t)(row0 + wave * 16 + (lane >> 2)) * K + (lane & 3) * 8;
    const int    a_l0   = (wave * 16 + (lane >> 2)) * 32 + (lane & 3) * 8;
    const size_t b_gbase = ((size_t)col0 + wave * 16 + (lane >> 2)) * 32 + (lane & 3) * 8;
    const int    b_l0   = (wave * 16 + (lane >> 2)) * 32 + (lane & 3) * 8;

    f32x4 acc[4][NT];
    #pragma unroll
    for (int mt = 0; mt < 4; ++mt)
        #pragma unroll
        for (int nt = 0; nt < NT; ++nt)
            acc[mt][nt] = (f32x4)0.f;

    const int KT = K / 32;
    for (int kt = 0; kt < KT; ++kt) {
        __syncthreads();
        GLL16(A + a_g0 + (size_t)kt * 32, As + a_l0);
        GLL16(A + a_g0 + (size_t)(kt * 32) + (size_t)64 * K, As + a_l0 + 64 * 32);
        const size_t bk = (size_t)kt * N * 32;
        GLL16(Wp + bk + b_gbase, Bs + b_l0);
        if (BN == 128)
            GLL16(Wp + bk + b_gbase + 64 * 32, Bs + b_l0 + 64 * 32);
        __syncthreads();

        bf16x8 af[4], bf[NT];
        #pragma unroll
        for (int mt = 0; mt < 4; ++mt)
            af[mt] = *(const bf16x8*)(As + (wr * 64 + mt * 16 + l15) * 32 + quad * 8);
        #pragma unroll
        for (int nt = 0; nt < NT; ++nt)
            bf[nt] = *(const bf16x8*)(Bs + (wc * (BN / 2) + nt * 16 + l15) * 32 + quad * 8);
        #pragma unroll
        for (int mt = 0; mt < 4; ++mt)
            #pragma unroll
            for (int nt = 0; nt < NT; ++nt)
                acc[mt][nt] = __builtin_amdgcn_mfma_f32_16x16x32_bf16(
                    af[mt], bf[nt], acc[mt][nt], 0, 0, 0);
    }

    #pragma unroll
    for (int mt = 0; mt < 4; ++mt) {
        const int gr0 = row0 + wr * 64 + mt * 16 + quad * 4;
        #pragma unroll
        for (int nt = 0; nt < NT; ++nt) {
            const int gc = col0 + wc * (BN / 2) + nt * 16 + l15;
            #pragma unroll
            for (int r = 0; r < 4; ++r) {
                int gr = gr0 + r;
                if (gr < M) C[(size_t)gr * N + gc] = f2bf(acc[mt][nt][r]);
            }
        }
    }
}

// ---------------- gather segment-sum, 256 channels, bf16 in / bf16 out -----------
template <bool EPI>
__global__ void gather256_kernel(const unsigned short* __restrict__ src,
                                 unsigned short* __restrict__ dst,
                                 const int* __restrict__ off, const int* __restrict__ col,
                                 const float* __restrict__ scale,
                                 const float* __restrict__ bias, int nrows) {
    int row = blockIdx.x * (blockDim.x >> 6) + (threadIdx.x >> 6);
    if (row >= nrows) return;
    int lane = threadIdx.x & 63;
    int s = off[row], e = off[row + 1];
    float ax = 0.f, ay = 0.f, az = 0.f, aw = 0.f;
    int j = s;
    for (; j + 1 < e; j += 2) {
        int sr0 = col[j], sr1 = col[j + 1];
        const ushort4 u0 = *(const ushort4*)(src + (size_t)sr0 * HID_CH + (lane << 2));
        const ushort4 u1 = *(const ushort4*)(src + (size_t)sr1 * HID_CH + (lane << 2));
        ax += bf2f(u0.x) + bf2f(u1.x); ay += bf2f(u0.y) + bf2f(u1.y);
        az += bf2f(u0.z) + bf2f(u1.z); aw += bf2f(u0.w) + bf2f(u1.w);
    }
    if (j < e) {
        const ushort4 u = *(const ushort4*)(src + (size_t)col[j] * HID_CH + (lane << 2));
        ax += bf2f(u.x); ay += bf2f(u.y); az += bf2f(u.z); aw += bf2f(u.w);
    }
    float sc = scale[row];
    float rx = ax * sc, ry = ay * sc, rz = az * sc, rw = aw * sc;
    if (EPI) {
        const float4 b = *(const float4*)(bias + (lane << 2));
        rx = fmaxf(rx + b.x, 0.f); ry = fmaxf(ry + b.y, 0.f);
        rz = fmaxf(rz + b.z, 0.f); rw = fmaxf(rw + b.w, 0.f);
    }
    ushort4 o;
    o.x = f2bf(rx); o.y = f2bf(ry); o.z = f2bf(rz); o.w = f2bf(rw);
    *(ushort4*)(dst + (size_t)row * HID_CH + (lane << 2)) = o;
}

// ---------------- gather segment-sum, 64 channels, bf16 in ----------------
template <bool LSM>
__global__ void gather64_kernel(const unsigned short* __restrict__ src, void* __restrict__ dstv,
                                const int* __restrict__ off, const int* __restrict__ col,
                                const float* __restrict__ scale,
                                const float* __restrict__ bias, int nrows) {
    int row = blockIdx.x * (blockDim.x >> 6) + (threadIdx.x >> 6);
    if (row >= nrows) return;
    int lane = threadIdx.x & 63;
    int s = off[row], e = off[row + 1];
    float acc = 0.f;
    int j = s;
    for (; j + 1 < e; j += 2) {
        int sr0 = col[j], sr1 = col[j + 1];
        acc += bf2f(src[(size_t)sr0 * OUT_CH + lane]) + bf2f(src[(size_t)sr1 * OUT_CH + lane]);
    }
    if (j < e) acc += bf2f(src[(size_t)col[j] * OUT_CH + lane]);
    float v = acc * scale[row];
    if (LSM) {
        v += bias[lane];
        float m = v;
        #pragma unroll
        for (int o = 32; o >= 1; o >>= 1) m = fmaxf(m, __shfl_xor(m, o));
        float ex = expf(v - m);
        float su = ex;
        #pragma unroll
        for (int o = 32; o >= 1; o >>= 1) su += __shfl_xor(su, o);
        ((float*)dstv)[(size_t)row * OUT_CH + lane] = v - m - logf(su);
    } else {
        ((unsigned short*)dstv)[(size_t)row * OUT_CH + lane] = f2bf(v);
    }
}

extern "C" void kernel_launch(void* const* d_in, const int* in_sizes, int n_in,
                              void* d_out, int out_size, void* d_ws, size_t ws_size,
                              hipStream_t stream) {
    const float* x  = (const float*)d_in[0];
    const int*   ei = (const int*)d_in[1];
    const float* W1 = (const float*)d_in[2];
    const float* b1 = (const float*)d_in[3];
    const float* W2 = (const float*)d_in[4];
    const float* b2 = (const float*)d_in[5];
    float* out = (float*)d_out;

    const int* node_idx  = ei;
    const int* hedge_idx = ei + NNZ_;

    const size_t RCAP = (size_t)M_PAD * IN_CH / 2;   // floats; 51.25 MB per region
    float* regionA = (float*)d_ws;
    float* regionB = regionA + RCAP;
    float* Dinv = regionB + RCAP;
    float* Binv = Dinv + N_NODES;
    int* cntN = (int*)(Binv + N_HEDGES);
    int* cntH = cntN + N_NODES;
    int* offN = cntH + N_HEDGES;
    int* offH = offN + N_NODES + 1;
    int* colN = offH + N_HEDGES + 1;
    int* colH = colN + NNZ_;
    unsigned short* Wp1 = (unsigned short*)(colH + NNZ_);
    unsigned short* Wp2 = Wp1 + IN_CH * HID_CH;
    int* bcntH = (int*)(Wp2 + HID_CH * OUT_CH);      // 400
    int* bcntN = bcntH + 400;                        // 400
    int* bcurH = bcntN + 400;                        // 400 (scan out -> cursors -> ends)
    int* bcurN = bcurH + 400;                        // 400

    // transient CSR-build records alias regionA (dead until GEMM1 writes h1)
    unsigned* recH = (unsigned*)regionA;             // NNZ
    unsigned* recN = recH + NNZ_;                    // NNZ

    unsigned short* x_bf  = (unsigned short*)regionB;            // M_PAD x 512
    unsigned short* h1_bf = (unsigned short*)regionA;            // M_PAD x 256
    unsigned short* m1_bf = (unsigned short*)regionB;            // 50000 x 256 (x dead)
    unsigned short* h2_bf = (unsigned short*)regionA;            // M_PAD x 256 (h1 dead)
    unsigned short* g_bf  = (unsigned short*)regionB;            // 50000 x 64 (m1 dead)
    unsigned short* m2_bf = (unsigned short*)regionB + (size_t)M_PAD * OUT_CH; // 50000 x 64

    // ---- CSR build (bucketed counting sort; no random global scatter) ----
    hipMemsetAsync(bcntH, 0, 800 * sizeof(int), stream);
    bhist_kernel<<<98, 1024, 0, stream>>>(node_idx, hedge_idx, bcntN, bcntH);
    scan_kernel<<<2, 1024, 0, stream>>>(bcntH, bcurH, bcntN, bcurN, NBK);
    bin_kernel<<<200, 1024, 0, stream>>>(node_idx, hedge_idx, bcurN, bcurH, recN, recH);
    fcnt_kernel<<<2 * NBK, 256, 0, stream>>>(bcurH, recH, bcurN, recN, cntH, cntN);
    inv_kernel<<<(N_NODES + 255) / 256, 256, 0, stream>>>(cntN, cntH, Dinv, Binv);
    scan_kernel<<<2, 1024, 0, stream>>>(cntH, offH, cntN, offN, N_NODES);
    fillcsr_kernel<<<2 * NBK, 256, 0, stream>>>(bcurH, recH, offH, colH,
                                                bcurN, recN, offN, colN);

    // ---- precision prep ----
    cvt_bf16_kernel<<<(N_NODES * IN_CH / 4 + 255) / 256, 256, 0, stream>>>(
        x, x_bf, (long)N_NODES * IN_CH / 4);
    pack_w_kernel<<<(IN_CH * HID_CH + 255) / 256, 256, 0, stream>>>(W1, Wp1, IN_CH, HID_CH);
    pack_w_kernel<<<(HID_CH * OUT_CH + 255) / 256, 256, 0, stream>>>(W2, Wp2, HID_CH, OUT_CH);

    // ---- layer 1: h1 = x @ W1 (MFMA bf16) ----
    mfma_gemm_kernel<128><<<dim3(HID_CH / 128, (N_NODES + 127) / 128), 256, 0, stream>>>(
        x_bf, Wp1, h1_bf, N_NODES, HID_CH, IN_CH);
    gather256_kernel<false><<<(N_HEDGES + 3) / 4, 256, 0, stream>>>(
        h1_bf, m1_bf, offH, colH, Binv, nullptr, N_HEDGES);
    gather256_kernel<true><<<(N_NODES + 3) / 4, 256, 0, stream>>>(
        m1_bf, h2_bf, offN, colN, Dinv, b1, N_NODES);

    // ---- layer 2: g = h2 @ W2 (MFMA bf16) ----
    mfma_gemm_kernel<64><<<dim3(OUT_CH / 64, (N_NODES + 127) / 128), 256, 0, stream>>>(
        h2_bf, Wp2, g_bf, N_NODES, OUT_CH, HID_CH);
    gather64_kernel<false><<<(N_HEDGES + 3) / 4, 256, 0, stream>>>(
        g_bf, m2_bf, offH, colH, Binv, nullptr, N_HEDGES);
    gather64_kernel<true><<<(N_NODES + 3) / 4, 256, 0, stream>>>(
        m2_bf, out, offN, colN, Dinv, b2, N_NODES);
}

// Round 7
// 505.830 us; speedup vs baseline: 14.5129x; 1.1415x over previous
//
#include <hip/hip_runtime.h>
#include <math.h>

#define N_NODES  50000
#define N_HEDGES 50000
#define NNZ_     800000
#define IN_CH    512
#define HID_CH   256
#define OUT_CH   64
#define M_PAD    50048   // 391*128 rows of staging slack for global_load_lds
#define NBK      391     // buckets of 128 ids: ceil(50000/128)
#define SSEG     1024    // scan segment (4 elems x 256 threads)
#define SBK      64      // scan blocks per array (64*1024 >= 50000)

typedef __attribute__((ext_vector_type(8))) short bf16x8;
typedef __attribute__((ext_vector_type(4))) float f32x4;

__device__ __forceinline__ unsigned short f2bf(float f) {
    union { float f; unsigned u; } v; v.f = f;
    unsigned r = v.u + 0x7FFFu + ((v.u >> 16) & 1u);   // round-to-nearest-even
    return (unsigned short)(r >> 16);
}
__device__ __forceinline__ float bf2f(unsigned short u) {
    union { unsigned u; float f; } v; v.u = (unsigned)u << 16; return v.f;
}

#define GLL16(g, l)                                                            \
    __builtin_amdgcn_global_load_lds(                                          \
        (const __attribute__((address_space(1))) void*)(g),                    \
        (__attribute__((address_space(3))) void*)(l), 16, 0, 0)

// ---------------- bucket histogram (both sides), LDS-aggregated ----------------
__global__ void bhist_kernel(const int* __restrict__ ni, const int* __restrict__ hi,
                             int* __restrict__ bcntN, int* __restrict__ bcntH) {
    __shared__ int lh[NBK], ln[NBK];
    for (int t = threadIdx.x; t < NBK; t += blockDim.x) { lh[t] = 0; ln[t] = 0; }
    __syncthreads();
    const int stride = gridDim.x * blockDim.x;           // in int4 units
    for (int i4 = blockIdx.x * blockDim.x + threadIdx.x; i4 < NNZ_ / 4; i4 += stride) {
        const int4 nv = *(const int4*)(ni + i4 * 4);
        const int4 hv = *(const int4*)(hi + i4 * 4);
        atomicAdd(&ln[nv.x >> 7], 1); atomicAdd(&ln[nv.y >> 7], 1);
        atomicAdd(&ln[nv.z >> 7], 1); atomicAdd(&ln[nv.w >> 7], 1);
        atomicAdd(&lh[hv.x >> 7], 1); atomicAdd(&lh[hv.y >> 7], 1);
        atomicAdd(&lh[hv.z >> 7], 1); atomicAdd(&lh[hv.w >> 7], 1);
    }
    __syncthreads();
    for (int t = threadIdx.x; t < NBK; t += blockDim.x) {
        if (ln[t]) atomicAdd(&bcntN[t], ln[t]);
        if (lh[t]) atomicAdd(&bcntH[t], lh[t]);
    }
}

// ---------------- small single-block scan (used for the 391-entry bucket scan) -----
__global__ void scan_kernel(const int* __restrict__ cntA, int* __restrict__ offA,
                            const int* __restrict__ cntB, int* __restrict__ offB, int n) {
    const int* cnt = blockIdx.x ? cntB : cntA;
    int* off = blockIdx.x ? offB : offA;
    __shared__ int sums[1024];
    const int t = threadIdx.x;
    const int CHUNK = (n + 1023) / 1024;
    const int start = t * CHUNK;
    const int end   = min(start + CHUNK, n);
    int local = 0;
    for (int i = start; i < end; ++i) local += cnt[i];
    sums[t] = local;
    __syncthreads();
    #pragma unroll
    for (int d = 1; d < 1024; d <<= 1) {
        int v = (t >= d) ? sums[t - d] : 0;
        __syncthreads();
        sums[t] += v;
        __syncthreads();
    }
    int run = (t == 0) ? 0 : sums[t - 1];
    for (int i = start; i < end; ++i) {
        off[i] = run;
        run += cnt[i];
    }
    if (t == 1023) off[n] = sums[1023];
}

// ---------------- hierarchical scan, phase 1: per-segment sums ----------------
__global__ void scanp1_kernel(const int* __restrict__ cntH, int* __restrict__ partH,
                              const int* __restrict__ cntN, int* __restrict__ partN, int n) {
    const int which = blockIdx.x >= SBK;
    const int* cnt = which ? cntN : cntH;
    int* part = which ? partN : partH;
    const int b = which ? blockIdx.x - SBK : blockIdx.x;
    const int s = b * SSEG;
    const int e = min(s + SSEG, n);
    const int i0 = s + 4 * (int)threadIdx.x;
    int sum = 0;
    if (i0 + 3 < e) {
        const int4 v = *(const int4*)(cnt + i0);
        sum = v.x + v.y + v.z + v.w;
    } else {
        for (int k = 0; k < 4; ++k) if (i0 + k < e) sum += cnt[i0 + k];
    }
    #pragma unroll
    for (int o = 32; o >= 1; o >>= 1) sum += __shfl_xor(sum, o);
    __shared__ int wsum[4];
    if ((threadIdx.x & 63) == 0) wsum[threadIdx.x >> 6] = sum;
    __syncthreads();
    if (threadIdx.x == 0) part[b] = wsum[0] + wsum[1] + wsum[2] + wsum[3];
}

// ---------------- phase 2: exclusive scan of 64 partials (one wave per array) ------
__global__ void scanp2_kernel(int* __restrict__ partH, int* __restrict__ offH,
                              int* __restrict__ partN, int* __restrict__ offN, int n) {
    int* part = blockIdx.x ? partN : partH;
    int* off  = blockIdx.x ? offN : offH;
    const int t = threadIdx.x;       // 64 threads
    const int v = part[t];
    int inc = v;
    #pragma unroll
    for (int d = 1; d < 64; d <<= 1) {
        int u = __shfl_up(inc, d);
        if (t >= d) inc += u;
    }
    part[t] = inc - v;               // exclusive prefix
    if (t == 63) off[n] = inc;       // grand total
}

// ---------------- phase 3: per-segment exclusive scan + writeback ----------------
__global__ void scanp3_kernel(const int* __restrict__ cntH, const int* __restrict__ partH,
                              int* __restrict__ offH,
                              const int* __restrict__ cntN, const int* __restrict__ partN,
                              int* __restrict__ offN, int n) {
    const int which = blockIdx.x >= SBK;
    const int* cnt = which ? cntN : cntH;
    const int* part = which ? partN : partH;
    int* off = which ? offN : offH;
    const int b = which ? blockIdx.x - SBK : blockIdx.x;
    const int s = b * SSEG;
    const int e = min(s + SSEG, n);
    if (s >= e) return;
    const int t = threadIdx.x;
    const int i0 = s + 4 * t;
    int v[4];
    int sum = 0;
    if (i0 + 3 < e) {
        const int4 q = *(const int4*)(cnt + i0);
        v[0] = q.x; v[1] = q.y; v[2] = q.z; v[3] = q.w;
        sum = q.x + q.y + q.z + q.w;
    } else {
        #pragma unroll
        for (int k = 0; k < 4; ++k) { v[k] = (i0 + k < e) ? cnt[i0 + k] : 0; sum += v[k]; }
    }
    __shared__ int sc[256];
    sc[t] = sum;
    __syncthreads();
    #pragma unroll
    for (int d = 1; d < 256; d <<= 1) {
        int u = (t >= d) ? sc[t - d] : 0;
        __syncthreads();
        sc[t] += u;
        __syncthreads();
    }
    int run = part[b] + sc[t] - sum;
    #pragma unroll
    for (int k = 0; k < 4; ++k) {
        if (i0 + k < e) off[i0 + k] = run;
        run += v[k];
    }
}

// ---------------- bin: scatter packed records into bucket slices ----------------
__global__ void bin_kernel(const int* __restrict__ ni, const int* __restrict__ hi,
                           int* __restrict__ bcurN, int* __restrict__ bcurH,
                           unsigned* __restrict__ recN, unsigned* __restrict__ recH) {
    __shared__ int cH[NBK], cN[NBK], bH[NBK], bN[NBK];
    for (int t = threadIdx.x; t < NBK; t += blockDim.x) { cH[t] = 0; cN[t] = 0; }
    __syncthreads();
    const int gid = blockIdx.x * blockDim.x + threadIdx.x;
    const int i0 = gid * 4;
    int4 nv, hv;
    const bool act = (i0 < NNZ_);
    if (act) {
        nv = *(const int4*)(ni + i0);
        hv = *(const int4*)(hi + i0);
        atomicAdd(&cN[nv.x >> 7], 1); atomicAdd(&cN[nv.y >> 7], 1);
        atomicAdd(&cN[nv.z >> 7], 1); atomicAdd(&cN[nv.w >> 7], 1);
        atomicAdd(&cH[hv.x >> 7], 1); atomicAdd(&cH[hv.y >> 7], 1);
        atomicAdd(&cH[hv.z >> 7], 1); atomicAdd(&cH[hv.w >> 7], 1);
    }
    __syncthreads();
    for (int t = threadIdx.x; t < NBK; t += blockDim.x) {
        bH[t] = cH[t] ? atomicAdd(&bcurH[t], cH[t]) : 0;
        bN[t] = cN[t] ? atomicAdd(&bcurN[t], cN[t]) : 0;
    }
    __syncthreads();
    for (int t = threadIdx.x; t < NBK; t += blockDim.x) { cH[t] = bH[t]; cN[t] = bN[t]; }
    __syncthreads();
    if (act) {
        int nn[4] = {nv.x, nv.y, nv.z, nv.w};
        int hh[4] = {hv.x, hv.y, hv.z, hv.w};
        #pragma unroll
        for (int k = 0; k < 4; ++k) {
            int p = atomicAdd(&cH[hh[k] >> 7], 1);
            recH[p] = ((unsigned)(hh[k] & 127) << 16) | (unsigned)nn[k];
            p = atomicAdd(&cN[nn[k] >> 7], 1);
            recN[p] = ((unsigned)(nn[k] & 127) << 16) | (unsigned)hh[k];
        }
    }
}

// ---- fine counts per id from binned records + fused inverse-degree write ----
__global__ void fcnt_kernel(const int* __restrict__ bcurH, const unsigned* __restrict__ recH,
                            const int* __restrict__ bcurN, const unsigned* __restrict__ recN,
                            int* __restrict__ cntH, int* __restrict__ cntN,
                            float* __restrict__ Binv, float* __restrict__ Dinv) {
    int b = blockIdx.x;
    const int* bcur; const unsigned* rec; int* cnt; float* inv;
    if (b < NBK) { bcur = bcurH; rec = recH; cnt = cntH; inv = Binv; }
    else         { b -= NBK; bcur = bcurN; rec = recN; cnt = cntN; inv = Dinv; }
    __shared__ int lc[128];
    if (threadIdx.x < 128) lc[threadIdx.x] = 0;
    __syncthreads();
    const int s = b ? bcur[b - 1] : 0;
    const int e = bcur[b];
    for (int i = s + threadIdx.x; i < e; i += blockDim.x)
        atomicAdd(&lc[rec[i] >> 16], 1);
    __syncthreads();
    const int id = b * 128 + threadIdx.x;
    if (threadIdx.x < 128 && id < N_NODES) {
        const int c = lc[threadIdx.x];
        cnt[id] = c;
        inv[id] = c > 0 ? 1.f / (float)c : 0.f;
    }
}

// ---------------- CSR fill from binned records (bucket-local writes) ----------------
__global__ void fillcsr_kernel(const int* __restrict__ bcurH, const unsigned* __restrict__ recH,
                               const int* __restrict__ offH, int* __restrict__ colH,
                               const int* __restrict__ bcurN, const unsigned* __restrict__ recN,
                               const int* __restrict__ offN, int* __restrict__ colN) {
    int b = blockIdx.x;
    const int* bcur; const unsigned* rec; const int* off; int* col;
    if (b < NBK) { bcur = bcurH; rec = recH; off = offH; col = colH; }
    else         { b -= NBK; bcur = bcurN; rec = recN; off = offN; col = colN; }
    __shared__ int cur[128];
    const int id = b * 128 + threadIdx.x;
    if (threadIdx.x < 128) cur[threadIdx.x] = (id < N_NODES) ? off[id] : 0;
    __syncthreads();
    const int s = b ? bcur[b - 1] : 0;
    const int e = bcur[b];
    for (int i = s + threadIdx.x; i < e; i += blockDim.x) {
        const unsigned r = rec[i];
        const int p = atomicAdd(&cur[r >> 16], 1);
        col[p] = (int)(r & 0xFFFFu);
    }
}

// ---------------- fp32 -> bf16 row-major convert (vectorized) ----------------
__global__ void cvt_bf16_kernel(const float* __restrict__ src,
                                unsigned short* __restrict__ dst, long n4) {
    long i = (long)blockIdx.x * blockDim.x + threadIdx.x;
    if (i >= n4) return;
    const float4 v = *(const float4*)(src + i * 4);
    ushort4 o;
    o.x = f2bf(v.x); o.y = f2bf(v.y); o.z = f2bf(v.z); o.w = f2bf(v.w);
    *(ushort4*)(dst + i * 4) = o;
}

// ---------------- W pack: Wp[kt][n][kk] (B-fragment order) ----------------
__global__ void pack_w_kernel(const float* __restrict__ W, unsigned short* __restrict__ Wp,
                              int K, int N) {
    int i = blockIdx.x * blockDim.x + threadIdx.x;
    if (i >= K * N) return;
    int kt = i / (N * 32);
    int r  = i % (N * 32);
    int n  = r >> 5;
    int kk = r & 31;
    Wp[i] = f2bf(W[(size_t)(kt * 32 + kk) * N + n]);
}

// ---------------- MFMA bf16 GEMM: C[M,N] = A[M,K] @ W[K,N], bf16 output -----------
template <int BN>
__global__ void mfma_gemm_kernel(const unsigned short* __restrict__ A,
                                 const unsigned short* __restrict__ Wp,
                                 unsigned short* __restrict__ C, int M, int N, int K) {
    constexpr int NT = BN / 32;
    __shared__ unsigned short As[128 * 32];
    __shared__ unsigned short Bs[BN * 32];

    const int tid  = threadIdx.x;
    const int wave = tid >> 6;
    const int lane = tid & 63;
    const int wr = wave >> 1;
    const int wc = wave & 1;
    const int quad = lane >> 4;
    const int l15  = lane & 15;
    const int row0 = blockIdx.y * 128;
    const int col0 = blockIdx.x * BN;

    const size_t a_g0   = (size_t)(row0 + wave * 16 + (lane >> 2)) * K + (lane & 3) * 8;
    const int    a_l0   = (wave * 16 + (lane >> 2)) * 32 + (lane & 3) * 8;
    const size_t b_gbase = ((size_t)col0 + wave * 16 + (lane >> 2)) * 32 + (lane & 3) * 8;
    const int    b_l0   = (wave * 16 + (lane >> 2)) * 32 + (lane & 3) * 8;

    f32x4 acc[4][NT];
    #pragma unroll
    for (int mt = 0; mt < 4; ++mt)
        #pragma unroll
        for (int nt = 0; nt < NT; ++nt)
            acc[mt][nt] = (f32x4)0.f;

    const int KT = K / 32;
    for (int kt = 0; kt < KT; ++kt) {
        __syncthreads();
        GLL16(A + a_g0 + (size_t)kt * 32, As + a_l0);
        GLL16(A + a_g0 + (size_t)(kt * 32) + (size_t)64 * K, As + a_l0 + 64 * 32);
        const size_t bk = (size_t)kt * N * 32;
        GLL16(Wp + bk + b_gbase, Bs + b_l0);
        if (BN == 128)
            GLL16(Wp + bk + b_gbase + 64 * 32, Bs + b_l0 + 64 * 32);
        __syncthreads();

        bf16x8 af[4], bf[NT];
        #pragma unroll
        for (int mt = 0; mt < 4; ++mt)
            af[mt] = *(const bf16x8*)(As + (wr * 64 + mt * 16 + l15) * 32 + quad * 8);
        #pragma unroll
        for (int nt = 0; nt < NT; ++nt)
            bf[nt] = *(const bf16x8*)(Bs + (wc * (BN / 2) + nt * 16 + l15) * 32 + quad * 8);
        #pragma unroll
        for (int mt = 0; mt < 4; ++mt)
            #pragma unroll
            for (int nt = 0; nt < NT; ++nt)
                acc[mt][nt] = __builtin_amdgcn_mfma_f32_16x16x32_bf16(
                    af[mt], bf[nt], acc[mt][nt], 0, 0, 0);
    }

    #pragma unroll
    for (int mt = 0; mt < 4; ++mt) {
        const int gr0 = row0 + wr * 64 + mt * 16 + quad * 4;
        #pragma unroll
        for (int nt = 0; nt < NT; ++nt) {
            const int gc = col0 + wc * (BN / 2) + nt * 16 + l15;
            #pragma unroll
            for (int r = 0; r < 4; ++r) {
                int gr = gr0 + r;
                if (gr < M) C[(size_t)gr * N + gc] = f2bf(acc[mt][nt][r]);
            }
        }
    }
}

// ---------------- gather segment-sum, 256 channels, bf16 in / bf16 out -----------
template <bool EPI>
__global__ void gather256_kernel(const unsigned short* __restrict__ src,
                                 unsigned short* __restrict__ dst,
                                 const int* __restrict__ off, const int* __restrict__ col,
                                 const float* __restrict__ scale,
                                 const float* __restrict__ bias, int nrows) {
    int row = blockIdx.x * (blockDim.x >> 6) + (threadIdx.x >> 6);
    if (row >= nrows) return;
    int lane = threadIdx.x & 63;
    int s = off[row], e = off[row + 1];
    float ax = 0.f, ay = 0.f, az = 0.f, aw = 0.f;
    int j = s;
    for (; j + 1 < e; j += 2) {
        int sr0 = col[j], sr1 = col[j + 1];
        const ushort4 u0 = *(const ushort4*)(src + (size_t)sr0 * HID_CH + (lane << 2));
        const ushort4 u1 = *(const ushort4*)(src + (size_t)sr1 * HID_CH + (lane << 2));
        ax += bf2f(u0.x) + bf2f(u1.x); ay += bf2f(u0.y) + bf2f(u1.y);
        az += bf2f(u0.z) + bf2f(u1.z); aw += bf2f(u0.w) + bf2f(u1.w);
    }
    if (j < e) {
        const ushort4 u = *(const ushort4*)(src + (size_t)col[j] * HID_CH + (lane << 2));
        ax += bf2f(u.x); ay += bf2f(u.y); az += bf2f(u.z); aw += bf2f(u.w);
    }
    float sc = scale[row];
    float rx = ax * sc, ry = ay * sc, rz = az * sc, rw = aw * sc;
    if (EPI) {
        const float4 b = *(const float4*)(bias + (lane << 2));
        rx = fmaxf(rx + b.x, 0.f); ry = fmaxf(ry + b.y, 0.f);
        rz = fmaxf(rz + b.z, 0.f); rw = fmaxf(rw + b.w, 0.f);
    }
    ushort4 o;
    o.x = f2bf(rx); o.y = f2bf(ry); o.z = f2bf(rz); o.w = f2bf(rw);
    *(ushort4*)(dst + (size_t)row * HID_CH + (lane << 2)) = o;
}

// ---------------- gather segment-sum, 64 channels, bf16 in ----------------
template <bool LSM>
__global__ void gather64_kernel(const unsigned short* __restrict__ src, void* __restrict__ dstv,
                                const int* __restrict__ off, const int* __restrict__ col,
                                const float* __restrict__ scale,
                                const float* __restrict__ bias, int nrows) {
    int row = blockIdx.x * (blockDim.x >> 6) + (threadIdx.x >> 6);
    if (row >= nrows) return;
    int lane = threadIdx.x & 63;
    int s = off[row], e = off[row + 1];
    float acc = 0.f;
    int j = s;
    for (; j + 1 < e; j += 2) {
        int sr0 = col[j], sr1 = col[j + 1];
        acc += bf2f(src[(size_t)sr0 * OUT_CH + lane]) + bf2f(src[(size_t)sr1 * OUT_CH + lane]);
    }
    if (j < e) acc += bf2f(src[(size_t)col[j] * OUT_CH + lane]);
    float v = acc * scale[row];
    if (LSM) {
        v += bias[lane];
        float m = v;
        #pragma unroll
        for (int o = 32; o >= 1; o >>= 1) m = fmaxf(m, __shfl_xor(m, o));
        float ex = expf(v - m);
        float su = ex;
        #pragma unroll
        for (int o = 32; o >= 1; o >>= 1) su += __shfl_xor(su, o);
        ((float*)dstv)[(size_t)row * OUT_CH + lane] = v - m - logf(su);
    } else {
        ((unsigned short*)dstv)[(size_t)row * OUT_CH + lane] = f2bf(v);
    }
}

extern "C" void kernel_launch(void* const* d_in, const int* in_sizes, int n_in,
                              void* d_out, int out_size, void* d_ws, size_t ws_size,
                              hipStream_t stream) {
    const float* x  = (const float*)d_in[0];
    const int*   ei = (const int*)d_in[1];
    const float* W1 = (const float*)d_in[2];
    const float* b1 = (const float*)d_in[3];
    const float* W2 = (const float*)d_in[4];
    const float* b2 = (const float*)d_in[5];
    float* out = (float*)d_out;

    const int* node_idx  = ei;
    const int* hedge_idx = ei + NNZ_;

    const size_t RCAP = (size_t)M_PAD * IN_CH / 2;   // floats; 51.25 MB per region
    float* regionA = (float*)d_ws;
    float* regionB = regionA + RCAP;
    float* Dinv = regionB + RCAP;
    float* Binv = Dinv + N_NODES;
    int* cntN = (int*)(Binv + N_HEDGES);
    int* cntH = cntN + N_NODES;
    int* offN = cntH + N_HEDGES;
    int* offH = offN + N_NODES + 1;
    int* colN = offH + N_HEDGES + 1;
    int* colH = colN + NNZ_;
    unsigned short* Wp1 = (unsigned short*)(colH + NNZ_);
    unsigned short* Wp2 = Wp1 + IN_CH * HID_CH;
    int* bcntH = (int*)(Wp2 + HID_CH * OUT_CH);      // 400
    int* bcntN = bcntH + 400;                        // 400
    int* bcurH = bcntN + 400;                        // 400
    int* bcurN = bcurH + 400;                        // 400
    int* partH = bcurN + 400;                        // 64
    int* partN = partH + SBK;                        // 64

    // transient CSR-build records alias regionA (dead until GEMM1 writes h1)
    unsigned* recH = (unsigned*)regionA;             // NNZ
    unsigned* recN = recH + NNZ_;                    // NNZ

    unsigned short* x_bf  = (unsigned short*)regionB;            // M_PAD x 512
    unsigned short* h1_bf = (unsigned short*)regionA;            // M_PAD x 256
    unsigned short* m1_bf = (unsigned short*)regionB;            // 50000 x 256 (x dead)
    unsigned short* h2_bf = (unsigned short*)regionA;            // M_PAD x 256 (h1 dead)
    unsigned short* g_bf  = (unsigned short*)regionB;            // 50000 x 64 (m1 dead)
    unsigned short* m2_bf = (unsigned short*)regionB + (size_t)M_PAD * OUT_CH; // 50000 x 64

    // ---- CSR build (bucketed counting sort; no random global scatter) ----
    hipMemsetAsync(bcntH, 0, 800 * sizeof(int), stream);
    bhist_kernel<<<98, 1024, 0, stream>>>(node_idx, hedge_idx, bcntN, bcntH);
    scan_kernel<<<2, 1024, 0, stream>>>(bcntH, bcurH, bcntN, bcurN, NBK);
    bin_kernel<<<200, 1024, 0, stream>>>(node_idx, hedge_idx, bcurN, bcurH, recN, recH);
    fcnt_kernel<<<2 * NBK, 256, 0, stream>>>(bcurH, recH, bcurN, recN, cntH, cntN, Binv, Dinv);
    // hierarchical exclusive scan of cntH/cntN -> offH/offN
    scanp1_kernel<<<2 * SBK, 256, 0, stream>>>(cntH, partH, cntN, partN, N_NODES);
    scanp2_kernel<<<2, 64, 0, stream>>>(partH, offH, partN, offN, N_NODES);
    scanp3_kernel<<<2 * SBK, 256, 0, stream>>>(cntH, partH, offH, cntN, partN, offN, N_NODES);
    fillcsr_kernel<<<2 * NBK, 256, 0, stream>>>(bcurH, recH, offH, colH,
                                                bcurN, recN, offN, colN);

    // ---- precision prep ----
    cvt_bf16_kernel<<<(N_NODES * IN_CH / 4 + 255) / 256, 256, 0, stream>>>(
        x, x_bf, (long)N_NODES * IN_CH / 4);
    pack_w_kernel<<<(IN_CH * HID_CH + 255) / 256, 256, 0, stream>>>(W1, Wp1, IN_CH, HID_CH);
    pack_w_kernel<<<(HID_CH * OUT_CH + 255) / 256, 256, 0, stream>>>(W2, Wp2, HID_CH, OUT_CH);

    // ---- layer 1: h1 = x @ W1 (MFMA bf16) ----
    mfma_gemm_kernel<128><<<dim3(HID_CH / 128, (N_NODES + 127) / 128), 256, 0, stream>>>(
        x_bf, Wp1, h1_bf, N_NODES, HID_CH, IN_CH);
    gather256_kernel<false><<<(N_HEDGES + 3) / 4, 256, 0, stream>>>(
        h1_bf, m1_bf, offH, colH, Binv, nullptr, N_HEDGES);
    gather256_kernel<true><<<(N_NODES + 3) / 4, 256, 0, stream>>>(
        m1_bf, h2_bf, offN, colN, Dinv, b1, N_NODES);

    // ---- layer 2: g = h2 @ W2 (MFMA bf16) ----
    mfma_gemm_kernel<64><<<dim3(OUT_CH / 64, (N_NODES + 127) / 128), 256, 0, stream>>>(
        h2_bf, Wp2, g_bf, N_NODES, OUT_CH, HID_CH);
    gather64_kernel<false><<<(N_HEDGES + 3) / 4, 256, 0, stream>>>(
        g_bf, m2_bf, offH, colH, Binv, nullptr, N_HEDGES);
    gather64_kernel<true><<<(N_NODES + 3) / 4, 256, 0, stream>>>(
        m2_bf, out, offN, colN, Dinv, b2, N_NODES);
}

// Round 8
// 433.171 us; speedup vs baseline: 16.9473x; 1.1677x over previous
//
#include <hip/hip_runtime.h>
#include <math.h>

#define N_NODES  50000
#define N_HEDGES 50000
#define NNZ_     800000
#define IN_CH    512
#define HID_CH   256
#define OUT_CH   64
#define M_PAD    50048   // 391*128 rows of staging slack for global_load_lds
#define NBK      391     // buckets of 128 ids: ceil(50000/128)

// prep kernel grid partition (256-thread blocks)
#define CVT_BLK  25000   // 50000*512/4 float4 / 256
#define BH_BLK   98
#define PK1_BLK  512     // 512*256/256
#define PK2_BLK  64      // 256*64/256

typedef __attribute__((ext_vector_type(8))) short bf16x8;
typedef __attribute__((ext_vector_type(4))) float f32x4;

__device__ __forceinline__ unsigned short f2bf(float f) {
    union { float f; unsigned u; } v; v.f = f;
    unsigned r = v.u + 0x7FFFu + ((v.u >> 16) & 1u);   // round-to-nearest-even
    return (unsigned short)(r >> 16);
}
__device__ __forceinline__ float bf2f(unsigned short u) {
    union { unsigned u; float f; } v; v.u = (unsigned)u << 16; return v.f;
}

#define GLL16(g, l)                                                            \
    __builtin_amdgcn_global_load_lds(                                          \
        (const __attribute__((address_space(1))) void*)(g),                    \
        (__attribute__((address_space(3))) void*)(l), 16, 0, 0)

// ---- prep: fused  x->bf16 convert | bucket histogram | W1 pack | W2 pack ----
__global__ void prep_kernel(const float* __restrict__ x, unsigned short* __restrict__ x_bf,
                            const float* __restrict__ W1, unsigned short* __restrict__ Wp1,
                            const float* __restrict__ W2, unsigned short* __restrict__ Wp2,
                            const int* __restrict__ ni, const int* __restrict__ hi,
                            int* __restrict__ bcntN, int* __restrict__ bcntH) {
    const int blk = blockIdx.x;
    const int t = threadIdx.x;
    if (blk < CVT_BLK) {
        const long i = (long)blk * 256 + t;
        const float4 v = *(const float4*)(x + i * 4);
        ushort4 o;
        o.x = f2bf(v.x); o.y = f2bf(v.y); o.z = f2bf(v.z); o.w = f2bf(v.w);
        *(ushort4*)(x_bf + i * 4) = o;
    } else if (blk < CVT_BLK + BH_BLK) {
        __shared__ int lh[NBK], ln[NBK];
        for (int k = t; k < NBK; k += 256) { lh[k] = 0; ln[k] = 0; }
        __syncthreads();
        const int bb = blk - CVT_BLK;
        for (int i4 = bb * 256 + t; i4 < NNZ_ / 4; i4 += BH_BLK * 256) {
            const int4 nv = *(const int4*)(ni + i4 * 4);
            const int4 hv = *(const int4*)(hi + i4 * 4);
            atomicAdd(&ln[nv.x >> 7], 1); atomicAdd(&ln[nv.y >> 7], 1);
            atomicAdd(&ln[nv.z >> 7], 1); atomicAdd(&ln[nv.w >> 7], 1);
            atomicAdd(&lh[hv.x >> 7], 1); atomicAdd(&lh[hv.y >> 7], 1);
            atomicAdd(&lh[hv.z >> 7], 1); atomicAdd(&lh[hv.w >> 7], 1);
        }
        __syncthreads();
        for (int k = t; k < NBK; k += 256) {
            if (ln[k]) atomicAdd(&bcntN[k], ln[k]);
            if (lh[k]) atomicAdd(&bcntH[k], lh[k]);
        }
    } else if (blk < CVT_BLK + BH_BLK + PK1_BLK) {
        const int i = (blk - (CVT_BLK + BH_BLK)) * 256 + t;
        const int kt = i / (HID_CH * 32);
        const int r  = i % (HID_CH * 32);
        const int n  = r >> 5, kk = r & 31;
        Wp1[i] = f2bf(W1[(size_t)(kt * 32 + kk) * HID_CH + n]);
    } else {
        const int i = (blk - (CVT_BLK + BH_BLK + PK1_BLK)) * 256 + t;
        const int kt = i / (OUT_CH * 32);
        const int r  = i % (OUT_CH * 32);
        const int n  = r >> 5, kk = r & 31;
        Wp2[i] = f2bf(W2[(size_t)(kt * 32 + kk) * OUT_CH + n]);
    }
}

// ---- 391-entry exclusive scan; writes bucket starts + a mutable cursor copy ----
__global__ void scan391_kernel(const int* __restrict__ cA, int* __restrict__ offA,
                               int* __restrict__ curA,
                               const int* __restrict__ cB, int* __restrict__ offB,
                               int* __restrict__ curB) {
    const int* cnt = blockIdx.x ? cB : cA;
    int* off = blockIdx.x ? offB : offA;
    int* cur = blockIdx.x ? curB : curA;
    __shared__ int sbuf[512];
    const int t = threadIdx.x;      // 512 threads
    const int v = (t < NBK) ? cnt[t] : 0;
    sbuf[t] = v;
    __syncthreads();
    #pragma unroll
    for (int d = 1; d < 512; d <<= 1) {
        int u = (t >= d) ? sbuf[t - d] : 0;
        __syncthreads();
        sbuf[t] += u;
        __syncthreads();
    }
    if (t < NBK) { off[t] = sbuf[t] - v; cur[t] = sbuf[t] - v; }
    if (t == NBK - 1) off[NBK] = sbuf[t];
}

// ---- bin: scatter packed records into bucket slices (mutates bcur cursors) ----
__global__ void bin_kernel(const int* __restrict__ ni, const int* __restrict__ hi,
                           int* __restrict__ bcurN, int* __restrict__ bcurH,
                           unsigned* __restrict__ recN, unsigned* __restrict__ recH) {
    __shared__ int cH[NBK], cN[NBK], bH[NBK], bN[NBK];
    for (int t = threadIdx.x; t < NBK; t += blockDim.x) { cH[t] = 0; cN[t] = 0; }
    __syncthreads();
    const int gid = blockIdx.x * blockDim.x + threadIdx.x;
    const int i0 = gid * 4;
    int4 nv, hv;
    const bool act = (i0 < NNZ_);
    if (act) {
        nv = *(const int4*)(ni + i0);
        hv = *(const int4*)(hi + i0);
        atomicAdd(&cN[nv.x >> 7], 1); atomicAdd(&cN[nv.y >> 7], 1);
        atomicAdd(&cN[nv.z >> 7], 1); atomicAdd(&cN[nv.w >> 7], 1);
        atomicAdd(&cH[hv.x >> 7], 1); atomicAdd(&cH[hv.y >> 7], 1);
        atomicAdd(&cH[hv.z >> 7], 1); atomicAdd(&cH[hv.w >> 7], 1);
    }
    __syncthreads();
    for (int t = threadIdx.x; t < NBK; t += blockDim.x) {
        bH[t] = cH[t] ? atomicAdd(&bcurH[t], cH[t]) : 0;
        bN[t] = cN[t] ? atomicAdd(&bcurN[t], cN[t]) : 0;
    }
    __syncthreads();
    for (int t = threadIdx.x; t < NBK; t += blockDim.x) { cH[t] = bH[t]; cN[t] = bN[t]; }
    __syncthreads();
    if (act) {
        int nn[4] = {nv.x, nv.y, nv.z, nv.w};
        int hh[4] = {hv.x, hv.y, hv.z, hv.w};
        #pragma unroll
        for (int k = 0; k < 4; ++k) {
            int p = atomicAdd(&cH[hh[k] >> 7], 1);
            recH[p] = ((unsigned)(hh[k] & 127) << 16) | (unsigned)nn[k];
            p = atomicAdd(&cN[nn[k] >> 7], 1);
            recN[p] = ((unsigned)(nn[k] & 127) << 16) | (unsigned)hh[k];
        }
    }
}

// ---- buildcsr: per bucket — count, 128-prefix-scan, off+inv write, col fill ----
__global__ void buildcsr_kernel(const int* __restrict__ bstartH, const unsigned* __restrict__ recH,
                                int* __restrict__ offH, int* __restrict__ colH,
                                float* __restrict__ Binv,
                                const int* __restrict__ bstartN, const unsigned* __restrict__ recN,
                                int* __restrict__ offN, int* __restrict__ colN,
                                float* __restrict__ Dinv) {
    int b = blockIdx.x;
    const int* bstart; const unsigned* rec; int* off; int* col; float* inv;
    if (b < NBK) { bstart = bstartH; rec = recH; off = offH; col = colH; inv = Binv; }
    else { b -= NBK; bstart = bstartN; rec = recN; off = offN; col = colN; inv = Dinv; }
    const int s = bstart[b], e = bstart[b + 1];
    const int t = threadIdx.x;
    __shared__ int lc[128], ps[128], cur[128];
    if (t < 128) lc[t] = 0;
    __syncthreads();
    for (int i = s + t; i < e; i += 256) atomicAdd(&lc[rec[i] >> 16], 1);
    __syncthreads();
    if (t < 128) ps[t] = lc[t];
    __syncthreads();
    #pragma unroll
    for (int d = 1; d < 128; d <<= 1) {
        int v = (t >= d && t < 128) ? ps[t - d] : 0;
        __syncthreads();
        if (t < 128) ps[t] += v;
        __syncthreads();
    }
    if (t < 128) {
        const int excl = s + ps[t] - lc[t];
        cur[t] = excl;
        const int id = b * 128 + t;
        if (id < N_NODES) {
            off[id] = excl;
            inv[id] = lc[t] > 0 ? 1.f / (float)lc[t] : 0.f;
        }
    }
    if (b == NBK - 1 && t == 255) off[N_NODES] = bstart[NBK];
    __syncthreads();
    for (int i = s + t; i < e; i += 256) {
        const unsigned r = rec[i];
        const int p = atomicAdd(&cur[r >> 16], 1);
        col[p] = (int)(r & 0xFFFFu);
    }
}

// ---------------- MFMA bf16 GEMM: C[M,N] = A[M,K] @ W[K,N], bf16 output -----------
template <int BN>
__global__ void mfma_gemm_kernel(const unsigned short* __restrict__ A,
                                 const unsigned short* __restrict__ Wp,
                                 unsigned short* __restrict__ C, int M, int N, int K) {
    constexpr int NT = BN / 32;
    __shared__ unsigned short As[128 * 32];
    __shared__ unsigned short Bs[BN * 32];

    const int tid  = threadIdx.x;
    const int wave = tid >> 6;
    const int lane = tid & 63;
    const int wr = wave >> 1;
    const int wc = wave & 1;
    const int quad = lane >> 4;
    const int l15  = lane & 15;
    const int row0 = blockIdx.y * 128;
    const int col0 = blockIdx.x * BN;

    const size_t a_g0   = (size_t)(row0 + wave * 16 + (lane >> 2)) * K + (lane & 3) * 8;
    const int    a_l0   = (wave * 16 + (lane >> 2)) * 32 + (lane & 3) * 8;
    const size_t b_gbase = ((size_t)col0 + wave * 16 + (lane >> 2)) * 32 + (lane & 3) * 8;
    const int    b_l0   = (wave * 16 + (lane >> 2)) * 32 + (lane & 3) * 8;

    f32x4 acc[4][NT];
    #pragma unroll
    for (int mt = 0; mt < 4; ++mt)
        #pragma unroll
        for (int nt = 0; nt < NT; ++nt)
            acc[mt][nt] = (f32x4)0.f;

    const int KT = K / 32;
    for (int kt = 0; kt < KT; ++kt) {
        __syncthreads();
        GLL16(A + a_g0 + (size_t)kt * 32, As + a_l0);
        GLL16(A + a_g0 + (size_t)(kt * 32) + (size_t)64 * K, As + a_l0 + 64 * 32);
        const size_t bk = (size_t)kt * N * 32;
        GLL16(Wp + bk + b_gbase, Bs + b_l0);
        if (BN == 128)
            GLL16(Wp + bk + b_gbase + 64 * 32, Bs + b_l0 + 64 * 32);
        __syncthreads();

        bf16x8 af[4], bf[NT];
        #pragma unroll
        for (int mt = 0; mt < 4; ++mt)
            af[mt] = *(const bf16x8*)(As + (wr * 64 + mt * 16 + l15) * 32 + quad * 8);
        #pragma unroll
        for (int nt = 0; nt < NT; ++nt)
            bf[nt] = *(const bf16x8*)(Bs + (wc * (BN / 2) + nt * 16 + l15) * 32 + quad * 8);
        #pragma unroll
        for (int mt = 0; mt < 4; ++mt)
            #pragma unroll
            for (int nt = 0; nt < NT; ++nt)
                acc[mt][nt] = __builtin_amdgcn_mfma_f32_16x16x32_bf16(
                    af[mt], bf[nt], acc[mt][nt], 0, 0, 0);
    }

    #pragma unroll
    for (int mt = 0; mt < 4; ++mt) {
        const int gr0 = row0 + wr * 64 + mt * 16 + quad * 4;
        #pragma unroll
        for (int nt = 0; nt < NT; ++nt) {
            const int gc = col0 + wc * (BN / 2) + nt * 16 + l15;
            #pragma unroll
            for (int r = 0; r < 4; ++r) {
                int gr = gr0 + r;
                if (gr < M) C[(size_t)gr * N + gc] = f2bf(acc[mt][nt][r]);
            }
        }
    }
}

// ---------------- gather segment-sum, 256 channels, bf16, 4-deep unrolled ----------
template <bool EPI>
__global__ void gather256_kernel(const unsigned short* __restrict__ src,
                                 unsigned short* __restrict__ dst,
                                 const int* __restrict__ off, const int* __restrict__ col,
                                 const float* __restrict__ scale,
                                 const float* __restrict__ bias, int nrows) {
    int row = blockIdx.x * (blockDim.x >> 6) + (threadIdx.x >> 6);
    if (row >= nrows) return;
    int lane = threadIdx.x & 63;
    int s = off[row], e = off[row + 1];
    float ax = 0.f, ay = 0.f, az = 0.f, aw = 0.f;
    int j = s;
    for (; j + 3 < e; j += 4) {
        const ushort4 u0 = *(const ushort4*)(src + (size_t)col[j]     * HID_CH + (lane << 2));
        const ushort4 u1 = *(const ushort4*)(src + (size_t)col[j + 1] * HID_CH + (lane << 2));
        const ushort4 u2 = *(const ushort4*)(src + (size_t)col[j + 2] * HID_CH + (lane << 2));
        const ushort4 u3 = *(const ushort4*)(src + (size_t)col[j + 3] * HID_CH + (lane << 2));
        ax += (bf2f(u0.x) + bf2f(u1.x)) + (bf2f(u2.x) + bf2f(u3.x));
        ay += (bf2f(u0.y) + bf2f(u1.y)) + (bf2f(u2.y) + bf2f(u3.y));
        az += (bf2f(u0.z) + bf2f(u1.z)) + (bf2f(u2.z) + bf2f(u3.z));
        aw += (bf2f(u0.w) + bf2f(u1.w)) + (bf2f(u2.w) + bf2f(u3.w));
    }
    for (; j < e; ++j) {
        const ushort4 u = *(const ushort4*)(src + (size_t)col[j] * HID_CH + (lane << 2));
        ax += bf2f(u.x); ay += bf2f(u.y); az += bf2f(u.z); aw += bf2f(u.w);
    }
    float sc = scale[row];
    float rx = ax * sc, ry = ay * sc, rz = az * sc, rw = aw * sc;
    if (EPI) {
        const float4 b = *(const float4*)(bias + (lane << 2));
        rx = fmaxf(rx + b.x, 0.f); ry = fmaxf(ry + b.y, 0.f);
        rz = fmaxf(rz + b.z, 0.f); rw = fmaxf(rw + b.w, 0.f);
    }
    ushort4 o;
    o.x = f2bf(rx); o.y = f2bf(ry); o.z = f2bf(rz); o.w = f2bf(rw);
    *(ushort4*)(dst + (size_t)row * HID_CH + (lane << 2)) = o;
}

// ---------------- gather segment-sum, 64 channels, bf16, 4-deep unrolled -----------
template <bool LSM>
__global__ void gather64_kernel(const unsigned short* __restrict__ src, void* __restrict__ dstv,
                                const int* __restrict__ off, const int* __restrict__ col,
                                const float* __restrict__ scale,
                                const float* __restrict__ bias, int nrows) {
    int row = blockIdx.x * (blockDim.x >> 6) + (threadIdx.x >> 6);
    if (row >= nrows) return;
    int lane = threadIdx.x & 63;
    int s = off[row], e = off[row + 1];
    float acc = 0.f;
    int j = s;
    for (; j + 3 < e; j += 4) {
        const float v0 = bf2f(src[(size_t)col[j]     * OUT_CH + lane]);
        const float v1 = bf2f(src[(size_t)col[j + 1] * OUT_CH + lane]);
        const float v2 = bf2f(src[(size_t)col[j + 2] * OUT_CH + lane]);
        const float v3 = bf2f(src[(size_t)col[j + 3] * OUT_CH + lane]);
        acc += (v0 + v1) + (v2 + v3);
    }
    for (; j < e; ++j) acc += bf2f(src[(size_t)col[j] * OUT_CH + lane]);
    float v = acc * scale[row];
    if (LSM) {
        v += bias[lane];
        float m = v;
        #pragma unroll
        for (int o = 32; o >= 1; o >>= 1) m = fmaxf(m, __shfl_xor(m, o));
        float ex = expf(v - m);
        float su = ex;
        #pragma unroll
        for (int o = 32; o >= 1; o >>= 1) su += __shfl_xor(su, o);
        ((float*)dstv)[(size_t)row * OUT_CH + lane] = v - m - logf(su);
    } else {
        ((unsigned short*)dstv)[(size_t)row * OUT_CH + lane] = f2bf(v);
    }
}

extern "C" void kernel_launch(void* const* d_in, const int* in_sizes, int n_in,
                              void* d_out, int out_size, void* d_ws, size_t ws_size,
                              hipStream_t stream) {
    const float* x  = (const float*)d_in[0];
    const int*   ei = (const int*)d_in[1];
    const float* W1 = (const float*)d_in[2];
    const float* b1 = (const float*)d_in[3];
    const float* W2 = (const float*)d_in[4];
    const float* b2 = (const float*)d_in[5];
    float* out = (float*)d_out;

    const int* node_idx  = ei;
    const int* hedge_idx = ei + NNZ_;

    const size_t RCAP = (size_t)M_PAD * IN_CH / 2;   // floats; 51.25 MB per region
    float* regionA = (float*)d_ws;
    float* regionB = regionA + RCAP;
    float* Dinv = regionB + RCAP;
    float* Binv = Dinv + N_NODES;
    int* offN = (int*)(Binv + N_HEDGES);             // N_NODES+1
    int* offH = offN + N_NODES + 1;                  // N_HEDGES+1
    int* colN = offH + N_HEDGES + 1;                 // NNZ
    int* colH = colN + NNZ_;                         // NNZ
    unsigned short* Wp1 = (unsigned short*)(colH + NNZ_);
    unsigned short* Wp2 = Wp1 + IN_CH * HID_CH;
    int* bcntH   = (int*)(Wp2 + HID_CH * OUT_CH);    // 400
    int* bcntN   = bcntH + 400;                      // 400
    int* bstartH = bcntN + 400;                      // 392 used
    int* bstartN = bstartH + 400;
    int* bcurH   = bstartN + 400;
    int* bcurN   = bcurH + 400;

    // transient CSR-build records alias regionA (dead until GEMM1 writes h1)
    unsigned* recH = (unsigned*)regionA;             // NNZ
    unsigned* recN = recH + NNZ_;                    // NNZ

    unsigned short* x_bf  = (unsigned short*)regionB;            // M_PAD x 512
    unsigned short* h1_bf = (unsigned short*)regionA;            // M_PAD x 256
    unsigned short* m1_bf = (unsigned short*)regionB;            // 50000 x 256 (x dead)
    unsigned short* h2_bf = (unsigned short*)regionA;            // M_PAD x 256 (h1 dead)
    unsigned short* g_bf  = (unsigned short*)regionB;            // 50000 x 64 (m1 dead)
    unsigned short* m2_bf = (unsigned short*)regionB + (size_t)M_PAD * OUT_CH; // 50000 x 64

    // ---- fused prep + CSR build ----
    hipMemsetAsync(bcntH, 0, 800 * sizeof(int), stream);
    prep_kernel<<<CVT_BLK + BH_BLK + PK1_BLK + PK2_BLK, 256, 0, stream>>>(
        x, x_bf, W1, Wp1, W2, Wp2, node_idx, hedge_idx, bcntN, bcntH);
    scan391_kernel<<<2, 512, 0, stream>>>(bcntH, bstartH, bcurH, bcntN, bstartN, bcurN);
    bin_kernel<<<200, 1024, 0, stream>>>(node_idx, hedge_idx, bcurN, bcurH, recN, recH);
    buildcsr_kernel<<<2 * NBK, 256, 0, stream>>>(bstartH, recH, offH, colH, Binv,
                                                 bstartN, recN, offN, colN, Dinv);

    // ---- layer 1: h1 = x @ W1 (MFMA bf16) ----
    mfma_gemm_kernel<128><<<dim3(HID_CH / 128, (N_NODES + 127) / 128), 256, 0, stream>>>(
        x_bf, Wp1, h1_bf, N_NODES, HID_CH, IN_CH);
    gather256_kernel<false><<<(N_HEDGES + 3) / 4, 256, 0, stream>>>(
        h1_bf, m1_bf, offH, colH, Binv, nullptr, N_HEDGES);
    gather256_kernel<true><<<(N_NODES + 3) / 4, 256, 0, stream>>>(
        m1_bf, h2_bf, offN, colN, Dinv, b1, N_NODES);

    // ---- layer 2: g = h2 @ W2 (MFMA bf16) ----
    mfma_gemm_kernel<64><<<dim3(OUT_CH / 64, (N_NODES + 127) / 128), 256, 0, stream>>>(
        h2_bf, Wp2, g_bf, N_NODES, OUT_CH, HID_CH);
    gather64_kernel<false><<<(N_HEDGES + 3) / 4, 256, 0, stream>>>(
        g_bf, m2_bf, offH, colH, Binv, nullptr, N_HEDGES);
    gather64_kernel<true><<<(N_NODES + 3) / 4, 256, 0, stream>>>(
        m2_bf, out, offN, colN, Dinv, b2, N_NODES);
}